// Round 22
// baseline (367.635 us; speedup 1.0000x reference)
//
#include <hip/hip_runtime.h>

#define NPTS 32768
#define HL   32768
#define NNB  15
#define KC   32
#define BCAP 32

typedef __attribute__((ext_vector_type(8))) short s16x8;
typedef __attribute__((ext_vector_type(4))) float f32x4;

typedef union { s16x8 v; unsigned u[4]; } pk8;

__device__ __forceinline__ float lrelu(float x){ return x > 0.0f ? x : 0.1f*x; }

__device__ __forceinline__ unsigned short bf16r(float x){
    union { float f; unsigned u; } a; a.f = x;
    unsigned r = a.u + 0x7FFF + ((a.u >> 16) & 1);
    return (unsigned short)(r >> 16);
}
__device__ __forceinline__ void bf16_hilo(float x, unsigned short& hi, unsigned short& lo){
    hi = bf16r(x);
    union { float f; unsigned u; } b; b.u = ((unsigned)hi) << 16;
    lo = bf16r(x - b.f);
}
__device__ __forceinline__ void fsplit2(float a, float b, unsigned &h, unsigned &l){
    unsigned ua = __float_as_uint(a), ub = __float_as_uint(b);
    unsigned ha = ua & 0xFFFF0000u, hb = ub & 0xFFFF0000u;
    float ra = a - __uint_as_float(ha);
    float rb = b - __uint_as_float(hb);
    h = (ha >> 16) | hb;
    l = (__float_as_uint(ra) >> 16) | (__float_as_uint(rb) & 0xFFFF0000u);
}
__device__ __forceinline__ void fsplit1(float a, unsigned short &h, unsigned short &l){
    unsigned ua = __float_as_uint(a);
    unsigned ha = ua & 0xFFFF0000u;
    float ra = a - __uint_as_float(ha);
    h = (unsigned short)(ua >> 16);
    l = (unsigned short)(__float_as_uint(ra) >> 16);
}
__device__ __forceinline__ float bf2f(unsigned short h, unsigned short l){
    return __uint_as_float(((unsigned)h)<<16) + __uint_as_float(((unsigned)l)<<16);
}
__device__ __forceinline__ float blo(unsigned u){ return __uint_as_float(u << 16); }
__device__ __forceinline__ float bhi(unsigned u){ return __uint_as_float(u & 0xFFFF0000u); }
__device__ __forceinline__ float us2f(unsigned short u){ return __uint_as_float(((unsigned)u)<<16); }

__device__ __forceinline__ void async_cp16(const unsigned short* g, unsigned short* l){
    __builtin_amdgcn_global_load_lds(
        (const __attribute__((address_space(1))) unsigned int*)g,
        (__attribute__((address_space(3))) unsigned int*)l,
        16, 0, 0);
}

__device__ __forceinline__ pk8 shuf32(const unsigned* p0, const unsigned* p1,
                                      int sel, int srcA, int srcB){
    pk8 o;
    int a0 = __builtin_amdgcn_ds_bpermute(srcA, (int)p0[0]);
    int a1 = __builtin_amdgcn_ds_bpermute(srcA, (int)p1[0]);
    o.u[0] = (unsigned)(sel ? a1 : a0);
    int b0 = __builtin_amdgcn_ds_bpermute(srcA, (int)p0[1]);
    int b1 = __builtin_amdgcn_ds_bpermute(srcA, (int)p1[1]);
    o.u[1] = (unsigned)(sel ? b1 : b0);
    int c0 = __builtin_amdgcn_ds_bpermute(srcB, (int)p0[0]);
    int c1 = __builtin_amdgcn_ds_bpermute(srcB, (int)p1[0]);
    o.u[2] = (unsigned)(sel ? c1 : c0);
    int d0 = __builtin_amdgcn_ds_bpermute(srcB, (int)p0[1]);
    int d1 = __builtin_amdgcn_ds_bpermute(srcB, (int)p1[1]);
    o.u[3] = (unsigned)(sel ? d1 : d0);
    return o;
}

// ---------------------------------------------------------------- init: zero counters + repack weights
__global__ void init_kernel(int* __restrict__ cnt,
                              const float* __restrict__ sw1, const float* __restrict__ pw1,
                              const float* __restrict__ sw2, const float* __restrict__ cw1,
                              const float* __restrict__ cw2, const float* __restrict__ dw1,
                              const float* __restrict__ dw2, const float* __restrict__ pw2,
                              const float* __restrict__ fw2, const float* __restrict__ fw3,
                              unsigned short* __restrict__ SW16,
                              unsigned short* __restrict__ pw1fH, unsigned short* __restrict__ pw1fL,
                              unsigned short* __restrict__ W16,
                              unsigned short* __restrict__ pw2fH, unsigned short* __restrict__ pw2fL,
                              float* __restrict__ fw2T, float* __restrict__ fw3T){
    int tid = blockIdx.x*256 + threadIdx.x;
    if (tid < 2*HL) cnt[tid] = 0;
    if (tid < 61440){
        int b = tid&7, ln = (tid>>3)&63, ot = (tid>>9)&3, f = tid>>11;
        int kt = f&1, nn = f>>1;
        int o = ot*16 + (ln&15), k = kt*32 + (ln>>4)*8 + b, c = k + 4;
        unsigned short hi, lo; bf16_hilo(sw1[(o*68+c)*15+nn], hi, lo);
        SW16[tid] = hi; SW16[61440+tid] = lo;
    }
    if (tid < 4096){
        int b = tid&7, ln = (tid>>3)&63, ot = (tid>>9)&3, kt2 = tid>>11;
        int o = ot*16 + (ln&15), k2 = kt2*32 + (ln>>4)*8 + b;
        float v = (k2 < 60) ? sw1[(o*68 + (k2&3))*15 + (k2>>2)] : 0.f;
        unsigned short hi, lo; bf16_hilo(v, hi, lo);
        SW16[122880+tid] = hi; SW16[126976+tid] = lo;
    }
    if (tid < 4096){
        int b = tid&7, ln = (tid>>3)&63, ot = (tid>>9)&3, kt = tid>>11;
        int o = ot*16 + (ln&15), k = kt*32 + (ln>>4)*8 + b;
        unsigned short hi, lo; bf16_hilo(sw2[o*64+k], hi, lo);
        SW16[131072+tid] = hi; SW16[135168+tid] = lo;
    }
    if (tid < 245760){
        int b = tid & 7, ln = (tid>>3)&63, ot = (tid>>9)&7, kt = (tid>>12)&3, nn = tid>>14;
        int o = ot*16 + (ln&15), k = kt*32 + (ln>>4)*8 + b;
        float v = pw1[(o*128 + k)*15 + nn];
        unsigned short hi, lo; bf16_hilo(v, hi, lo);
        pw1fH[tid] = hi; pw1fL[tid] = lo;
    }
    if (tid < 16384){
        int b = tid & 7, ln = (tid>>3)&63, ot = (tid>>9)&7, kt = (tid>>12)&3;
        int o = ot*16 + (ln&15), k = kt*32 + (ln>>4)*8 + b;
        float v = pw2[o*128 + k];
        unsigned short hi, lo; bf16_hilo(v, hi, lo);
        pw2fH[tid] = hi; pw2fL[tid] = lo;
    }
    if (tid < 2048){
        int b = tid&7, ln = (tid>>3)&63, f = tid>>9;
        int ot = f>>1, kt = f&1;
        int o = ot*16 + (ln&15), c = kt*32 + (ln>>4)*8 + b;
        unsigned short hi, lo; bf16_hilo(cw1[o*64+c], hi, lo);
        W16[tid] = hi; W16[2048+tid] = lo;
    }
    if (tid < 1024){
        int b = tid&7, ln = (tid>>3)&63, ot = tid>>9;
        int o = ot*16 + (ln&15), c = (ln>>4)*8 + b;
        unsigned short hi, lo; bf16_hilo(cw2[o*32+c], hi, lo);
        W16[4096+tid] = hi; W16[5120+tid] = lo;
    }
    if (tid < 2048){
        int b = tid&7, ln = (tid>>3)&63, ot = tid>>9;
        int o = ot*16 + (ln&15), c = (ln>>4)*8 + b;
        unsigned short hi, lo; bf16_hilo(dw1[o*32+c], hi, lo);
        W16[6144+tid] = hi; W16[8192+tid] = lo;
    }
    if (tid < 4096){
        int b = tid&7, ln = (tid>>3)&63, f = tid>>9;
        int ot = f>>1, kt = f&1;
        int o = ot*16 + (ln&15), c = kt*32 + (ln>>4)*8 + b;
        unsigned short hi, lo; bf16_hilo(dw2[o*64+c], hi, lo);
        W16[10240+tid] = hi; W16[14336+tid] = lo;
    }
    if (tid < 16384){ int c = tid>>7, o = tid&127; fw2T[tid] = fw2[o*128+c]; }
    if (tid < 8192){ int c = tid>>6, o = tid&63; fw3T[tid] = fw3[o*128+c]; }
}

// ---------------------------------------------------------------- point MLP (both clouds) -> bf16 rows [el4][feat64][pad4]
__global__ __launch_bounds__(256) void mlp3_kernel(
        const float* __restrict__ pc1, const float* __restrict__ el1,
        const float* __restrict__ pc2, const float* __restrict__ el2,
        const float* __restrict__ w1, const float* __restrict__ b1,
        const float* __restrict__ w2, const float* __restrict__ b2,
        const float* __restrict__ w3, const float* __restrict__ b3,
        unsigned short* __restrict__ pf1, unsigned short* __restrict__ pf2){
    __shared__ float W1[96], W2s[1024], W3s[2048], B1[32], B2[32], B3[64];
    const int t = threadIdx.x;
    const int side = (int)(blockIdx.x >= 128);
    const float* pc = side ? pc2 : pc1;
    const float* el = side ? el2 : el1;
    unsigned short* pfeat = side ? pf2 : pf1;
    for (int e=t;e<96;e+=256)   W1[e]=w1[e];
    for (int e=t;e<1024;e+=256) W2s[e]=w2[e];
    for (int e=t;e<2048;e+=256) W3s[e]=w3[e];
    if (t<32){ B1[t]=b1[t]; B2[t]=b2[t]; }
    if (t<64){ B3[t]=b3[t]; }
    __syncthreads();
    const int n = (blockIdx.x & 127)*256 + t;
    const float x0 = pc[n], x1 = pc[NPTS+n], x2 = pc[2*NPTS+n];
    float h1[32];
    #pragma unroll
    for (int o=0;o<32;++o)
        h1[o] = lrelu(B1[o] + W1[o*3]*x0 + W1[o*3+1]*x1 + W1[o*3+2]*x2);
    float h2[32];
    #pragma unroll
    for (int o=0;o<32;++o){
        float a = B2[o];
        #pragma unroll
        for (int c=0;c<32;++c) a += W2s[o*32+c]*h1[c];
        h2[o] = lrelu(a);
    }
    unsigned short* row = pfeat + (size_t)n*72;
    *(ushort4*)row = make_ushort4(bf16r(el[n]), bf16r(el[NPTS+n]),
                                  bf16r(el[2*NPTS+n]), bf16r(el[3*NPTS+n]));
    #pragma unroll
    for (int o4=0;o4<16;++o4){
        float tmp[4];
        #pragma unroll
        for (int q=0;q<4;++q){
            const int o = o4*4+q;
            float a = B3[o];
            #pragma unroll
            for (int c=0;c<32;++c) a += W3s[o*32+c]*h2[c];
            tmp[q] = lrelu(a);
        }
        *(ushort4*)(row + 4 + o4*4) = make_ushort4(bf16r(tmp[0]), bf16r(tmp[1]),
                                                   bf16r(tmp[2]), bf16r(tmp[3]));
    }
    *(ushort4*)(row + 68) = make_ushort4(0,0,0,0);
}

// ---------------------------------------------------------------- bucket build (inverse map)
__global__ __launch_bounds__(256) void bucket_kernel(
        const float* __restrict__ bary1, const float* __restrict__ bary2,
        const int* __restrict__ off1, const int* __restrict__ off2,
        int* __restrict__ cnt,
        int* __restrict__ bnA, float* __restrict__ bvA,
        int* __restrict__ bnB, float* __restrict__ bvB){
    const int tid = blockIdx.x*256 + threadIdx.x;
    const int side = (int)(tid >= 5*NPTS);
    const int p = tid - side*5*NPTS;
    const float b = side ? bary2[p] : bary1[p];
    const int h = side ? off2[p] : off1[p];
    int* bn = side ? bnB : bnA;
    float* bv = side ? bvB : bvA;
    const int slot = atomicAdd(&cnt[side*HL + h], 1);
    if (slot < BCAP){
        bn[h*BCAP + slot] = p & (NPTS-1);
        bv[h*BCAP + slot] = b;
    }
}

// ---------------------------------------------------------------- splat2: gather bf16 pfeat rows -> compact bf16-hi lattice
// lattice row (72 ushorts): [featH 64][elH 4][pad 4]
__global__ __launch_bounds__(256) void splat2_kernel(
        const unsigned short* __restrict__ pf1, const unsigned short* __restrict__ pf2,
        const int* __restrict__ cnt,
        const int* __restrict__ bnA, const float* __restrict__ bvA,
        const int* __restrict__ bnB, const float* __restrict__ bvB,
        unsigned short* __restrict__ latA16, unsigned short* __restrict__ latB16){
    const int gw = (blockIdx.x*256 + threadIdx.x) >> 6;
    const int lane = threadIdx.x & 63;
    const int side = (int)(gw >= HL);
    const int h = gw - side*HL;
    const unsigned short* pfeat = side ? pf2 : pf1;
    const int* bn = side ? bnB : bnA;
    const float* bv = side ? bvB : bvA;
    unsigned short* lat = side ? latB16 : latA16;
    int c = cnt[side*HL + h]; if (c > BCAP) c = BCAP;
    float accF = 0.f, accE = 0.f;
    if (c > 0){
        int n = bn[h*BCAP];
        float b = bv[h*BCAP];
        for (int i=0; i<c; ++i){
            int n2 = 0; float b2 = 0.f;
            if (i+1 < c){ n2 = bn[h*BCAP+i+1]; b2 = bv[h*BCAP+i+1]; }
            const unsigned short* row = pfeat + (size_t)n*72;
            accF += b * us2f(row[4+lane]);
            if (lane < 4) accE += b * us2f(row[lane]);
            n = n2; b = b2;
        }
    }
    lat[(size_t)h*72 + lane] = bf16r(accF);
    if (lane < 4) lat[(size_t)h*72 + 64 + lane] = bf16r(accE);
    if (lane >= 60 && lane < 64) lat[(size_t)h*72 + 8 + lane] = 0;   // pad 68..71
}

// ---------------------------------------------------------------- blur_s: async global_load_lds feat staging (swizzled source), reg-staged el
__global__ __launch_bounds__(256) void blur_s_mfma_kernel(
        const unsigned short* __restrict__ latA16, const unsigned short* __restrict__ latB16,
        const int* __restrict__ nb1, const int* __restrict__ nb2,
        const unsigned short* __restrict__ SW16,
        const float* __restrict__ sb1, const float* __restrict__ sb2,
        unsigned short* __restrict__ lat2b, unsigned short* __restrict__ catHL){
    __shared__ __align__(16) unsigned short GH[2][2048];
    __shared__ __align__(16) unsigned short EH[2048];
    __shared__ int sidx[NNB][32];
    const int side = (int)(blockIdx.x >= 1024);
    const unsigned short* lat = side ? latB16 : latA16;
    const int* nb = side ? nb2 : nb1;
    const int t = threadIdx.x;
    const int hb = (blockIdx.x & 1023)*32;
    const int w = t>>6, lane = t&63;
    const int l15 = lane&15, lg = lane>>4;
    const int rowS = t>>3, qS = t&7;
    const int srcOff = (qS ^ (rowS&7))*8;   // swizzle applied at the SOURCE
    for (int e=t; e<NNB*32; e+=256) sidx[e>>5][e&31] = nb[(e>>5)*HL + hb + (e&31)];
    {
        const uint4 z4 = {0,0,0,0};
        *(uint4*)(EH + t*8) = z4;
    }
    __syncthreads();
#define FSTAGE(NN_,BUF_) { \
        const int g_ = sidx[NN_][rowS]; \
        async_cp16(lat + (size_t)g_*72 + srcOff, GH[BUF_] + w*512); }
#define ELOAD(Re_,NN_) { \
        if (t < 32) Re_ = *(const uint2*)(lat + (size_t)sidx[NN_][t]*72 + 64); }
#define EWRITE(Re_,NN_) { \
        if (t < 32){ \
            const int d_ = t*64 + ((((NN_)>>1) ^ (t&7))*8) + (((NN_)&1)*4); \
            *(uint2*)(EH + d_) = Re_; } }
#define SCOMPUTE(NN_,BUF_) { \
        _Pragma("unroll") \
        for (int kt=0; kt<2; ++kt){ \
            s16x8 BH[2]; \
            _Pragma("unroll") \
            for (int ht=0; ht<2; ++ht){ \
                const int h_ = ht*16 + l15; \
                const int qq_ = kt*4 + lg; \
                const int d_ = h_*64 + ((qq_ ^ (h_&7))*8); \
                BH[ht] = *(const s16x8*)(GH[BUF_] + d_); } \
            const int f_ = (NN_)*2 + kt; \
            const s16x8 AH = *(const s16x8*)(SW16 + (f_*4+w)*512 + lane*8); \
            const s16x8 AL = *(const s16x8*)(SW16 + 61440 + (f_*4+w)*512 + lane*8); \
            _Pragma("unroll") \
            for (int ht=0; ht<2; ++ht){ \
                acc[ht] = __builtin_amdgcn_mfma_f32_16x16x32_bf16(AH, BH[ht], acc[ht], 0,0,0); \
                acc[ht] = __builtin_amdgcn_mfma_f32_16x16x32_bf16(AL, BH[ht], acc[ht], 0,0,0); } } }
    uint2 Ae, Be;
    FSTAGE(0,0)
    ELOAD(Ae,0)
    __syncthreads();
    const f32x4 z = {0.f,0.f,0.f,0.f};
    f32x4 acc[2] = {z,z};
    #pragma unroll 1
    for (int nn=0; nn<NNB; ++nn){
        const int cur = nn&1;
        if (nn+1 < NNB) FSTAGE((nn+1),(cur^1))
        EWRITE(Ae,nn)
        if (nn+1 < NNB) ELOAD(Be,(nn+1))
        SCOMPUTE(nn,cur)
        __syncthreads();
        Ae = Be;
    }
#undef FSTAGE
#undef ELOAD
#undef EWRITE
#undef SCOMPUTE
    // el GEMM (K=64 packed across nn, hi-only B)
    #pragma unroll
    for (int kt2=0; kt2<2; ++kt2){
        s16x8 BH[2];
        #pragma unroll
        for (int ht=0; ht<2; ++ht){
            const int h = ht*16 + l15;
            const int qq = kt2*4 + lg;
            const int d = h*64 + ((qq ^ (h&7))*8);
            BH[ht] = *(const s16x8*)(EH + d);
        }
        const s16x8 AH = *(const s16x8*)(SW16 + 122880 + (kt2*4+w)*512 + lane*8);
        const s16x8 AL = *(const s16x8*)(SW16 + 126976 + (kt2*4+w)*512 + lane*8);
        #pragma unroll
        for (int ht=0; ht<2; ++ht){
            acc[ht] = __builtin_amdgcn_mfma_f32_16x16x32_bf16(AH, BH[ht], acc[ht], 0,0,0);
            acc[ht] = __builtin_amdgcn_mfma_f32_16x16x32_bf16(AL, BH[ht], acc[ht], 0,0,0);
        }
    }
    // T = lrelu(acc + sb1) -> hi in GH[0], lo in GH[1]
    {
        const int o0 = w*16 + lg*4;
        float bs1v[4];
        #pragma unroll
        for (int j=0;j<4;++j) bs1v[j] = sb1[o0+j];
        const int q16 = o0>>3;
        #pragma unroll
        for (int ht=0; ht<2; ++ht){
            const int h = ht*16 + l15;
            unsigned short th[4], tl[4];
            #pragma unroll
            for (int j=0;j<4;++j) bf16_hilo(lrelu(acc[ht][j] + bs1v[j]), th[j], tl[j]);
            const int d = h*64 + ((q16 ^ (h&7))*8) + (o0&7);
            *(ushort4*)(GH[0] + d) = make_ushort4(th[0],th[1],th[2],th[3]);
            *(ushort4*)(GH[1] + d) = make_ushort4(tl[0],tl[1],tl[2],tl[3]);
        }
    }
    __syncthreads();
    f32x4 acc2[2] = {z,z};
    #pragma unroll
    for (int kt=0; kt<2; ++kt){
        s16x8 BH[2], BL[2];
        #pragma unroll
        for (int ht=0; ht<2; ++ht){
            const int h = ht*16 + l15;
            const int qq = kt*4 + lg;
            const int d = h*64 + ((qq ^ (h&7))*8);
            BH[ht] = *(const s16x8*)(GH[0] + d);
            BL[ht] = *(const s16x8*)(GH[1] + d);
        }
        const s16x8 AH = *(const s16x8*)(SW16 + 131072 + (kt*4+w)*512 + lane*8);
        const s16x8 AL = *(const s16x8*)(SW16 + 135168 + (kt*4+w)*512 + lane*8);
        #pragma unroll
        for (int ht=0; ht<2; ++ht){
            acc2[ht] = __builtin_amdgcn_mfma_f32_16x16x32_bf16(AH, BH[ht], acc2[ht], 0,0,0);
            acc2[ht] = __builtin_amdgcn_mfma_f32_16x16x32_bf16(AH, BL[ht], acc2[ht], 0,0,0);
            acc2[ht] = __builtin_amdgcn_mfma_f32_16x16x32_bf16(AL, BH[ht], acc2[ht], 0,0,0);
        }
    }
    {
        const int o0 = w*16 + lg*4;
        float bs2v[4];
        #pragma unroll
        for (int j=0;j<4;++j) bs2v[j] = sb2[o0+j];
        #pragma unroll
        for (int ht=0; ht<2; ++ht){
            const int h = hb + ht*16 + l15;
            float v0 = lrelu(acc2[ht][0]+bs2v[0]), v1 = lrelu(acc2[ht][1]+bs2v[1]);
            float v2 = lrelu(acc2[ht][2]+bs2v[2]), v3 = lrelu(acc2[ht][3]+bs2v[3]);
            if (side){
                *(ushort4*)(lat2b + (size_t)h*64 + o0) =
                    make_ushort4(bf16r(v0), bf16r(v1), bf16r(v2), bf16r(v3));
            } else {
                unsigned short th[4], tl[4];
                bf16_hilo(v0, th[0], tl[0]); bf16_hilo(v1, th[1], tl[1]);
                bf16_hilo(v2, th[2], tl[2]); bf16_hilo(v3, th[3], tl[3]);
                *(ushort4*)(catHL + (size_t)h*256 + o0) = make_ushort4(th[0],th[1],th[2],th[3]);
                *(ushort4*)(catHL + (size_t)h*256 + 128 + o0) = make_ushort4(tl[0],tl[1],tl[2],tl[3]);
            }
        }
    }
}

// ---------------------------------------------------------------- corr step (bf16-hi gather, named reg banks, deep prefetch)
__device__ __forceinline__ void corr_step(
        uint4& Gl, uint4& Gh, int& idxq, int knext,
        const unsigned short* __restrict__ lat2b, const int* __restrict__ ci, int hcol, int lg,
        const float* l1f, const float* cb1r, const float* cb2r,
        const s16x8 (&C1H)[2][2], const s16x8 (&C1L)[2][2],
        const s16x8 (&C2H)[2], const s16x8 (&C2L)[2],
        int sel, int srcA, int srcB, float* agg){
    const f32x4 z = {0.f,0.f,0.f,0.f};
    float p[16];
    p[0]=l1f[0]*blo(Gl.x);  p[1]=l1f[1]*bhi(Gl.x);
    p[2]=l1f[2]*blo(Gl.y);  p[3]=l1f[3]*bhi(Gl.y);
    p[4]=l1f[4]*blo(Gl.z);  p[5]=l1f[5]*bhi(Gl.z);
    p[6]=l1f[6]*blo(Gl.w);  p[7]=l1f[7]*bhi(Gl.w);
    p[8]=l1f[8]*blo(Gh.x);  p[9]=l1f[9]*bhi(Gh.x);
    p[10]=l1f[10]*blo(Gh.y); p[11]=l1f[11]*bhi(Gh.y);
    p[12]=l1f[12]*blo(Gh.z); p[13]=l1f[13]*bhi(Gh.z);
    p[14]=l1f[14]*blo(Gh.w); p[15]=l1f[15]*bhi(Gh.w);
    {
        const unsigned short* r = lat2b + (size_t)idxq*64 + lg*8;
        Gl = *(const uint4*)r;
        Gh = *(const uint4*)(r + 32);
    }
    idxq = ci[knext*HL + hcol];
    pk8 BH[2], BL[2];
    #pragma unroll
    for (int kt=0; kt<2; ++kt)
        #pragma unroll
        for (int q=0; q<4; ++q)
            fsplit2(p[kt*8+2*q], p[kt*8+2*q+1], BH[kt].u[q], BL[kt].u[q]);
    f32x4 a1[2] = {z, z};
    #pragma unroll
    for (int kt=0; kt<2; ++kt){
        a1[0] = __builtin_amdgcn_mfma_f32_16x16x32_bf16(C1H[0][kt], BH[kt].v, a1[0], 0,0,0);
        a1[1] = __builtin_amdgcn_mfma_f32_16x16x32_bf16(C1H[1][kt], BH[kt].v, a1[1], 0,0,0);
        a1[0] = __builtin_amdgcn_mfma_f32_16x16x32_bf16(C1H[0][kt], BL[kt].v, a1[0], 0,0,0);
        a1[1] = __builtin_amdgcn_mfma_f32_16x16x32_bf16(C1H[1][kt], BL[kt].v, a1[1], 0,0,0);
        a1[0] = __builtin_amdgcn_mfma_f32_16x16x32_bf16(C1L[0][kt], BH[kt].v, a1[0], 0,0,0);
        a1[1] = __builtin_amdgcn_mfma_f32_16x16x32_bf16(C1L[1][kt], BH[kt].v, a1[1], 0,0,0);
    }
    unsigned mh[2][2], ml[2][2];
    #pragma unroll
    for (int ot=0; ot<2; ++ot)
        #pragma unroll
        for (int j=0; j<2; ++j)
            fsplit2(lrelu(a1[ot][2*j]   + cb1r[ot*4+2*j]),
                    lrelu(a1[ot][2*j+1] + cb1r[ot*4+2*j+1]), mh[ot][j], ml[ot][j]);
    pk8 B2H = shuf32(mh[0], mh[1], sel, srcA, srcB);
    pk8 B2L = shuf32(ml[0], ml[1], sel, srcA, srcB);
    f32x4 a2[2] = {z, z};
    a2[0] = __builtin_amdgcn_mfma_f32_16x16x32_bf16(C2H[0], B2H.v, a2[0], 0,0,0);
    a2[1] = __builtin_amdgcn_mfma_f32_16x16x32_bf16(C2H[1], B2H.v, a2[1], 0,0,0);
    a2[0] = __builtin_amdgcn_mfma_f32_16x16x32_bf16(C2H[0], B2L.v, a2[0], 0,0,0);
    a2[1] = __builtin_amdgcn_mfma_f32_16x16x32_bf16(C2H[1], B2L.v, a2[1], 0,0,0);
    a2[0] = __builtin_amdgcn_mfma_f32_16x16x32_bf16(C2L[0], B2H.v, a2[0], 0,0,0);
    a2[1] = __builtin_amdgcn_mfma_f32_16x16x32_bf16(C2L[1], B2H.v, a2[1], 0,0,0);
    #pragma unroll
    for (int i=0;i<8;++i)
        agg[i] += lrelu(a2[i>>2][i&3] + cb2r[i]);
}

// ---------------------------------------------------------------- corr + d-MLP, 4-way split-K (32 waves/CU) + deep prefetch
__global__ __launch_bounds__(256, 8) void corr_mfma_kernel(
        const unsigned short* __restrict__ lat2b, const int* __restrict__ ci,
        const unsigned short* __restrict__ W16,
        const float* __restrict__ cb1, const float* __restrict__ cb2,
        const float* __restrict__ db1, const float* __restrict__ db2,
        unsigned short* __restrict__ catHL){
    __shared__ float AGG[3][64][8];
    const int t = threadIdx.x;
    const int lane = t & 63;
    const int l15 = lane & 15, lg = lane >> 4;
    const int w = t >> 6;                 // 0..3 = K-quarter
    const int hcol = blockIdx.x*16 + l15; // 2048 blocks x 16 cols
    const int srcA = (l15 + ((lg&1)*32)) * 4;
    const int srcB = srcA + 64;
    const int sel = (lg>>1) & 1;

    s16x8 C1H[2][2], C1L[2][2], C2H[2], C2L[2];
    #pragma unroll
    for (int ot=0; ot<2; ++ot){
        #pragma unroll
        for (int kt=0; kt<2; ++kt){
            C1H[ot][kt] = *(const s16x8*)(W16 + (ot*2+kt)*512 + lane*8);
            C1L[ot][kt] = *(const s16x8*)(W16 + 2048 + (ot*2+kt)*512 + lane*8);
        }
        C2H[ot] = *(const s16x8*)(W16 + 4096 + ot*512 + lane*8);
        C2L[ot] = *(const s16x8*)(W16 + 5120 + ot*512 + lane*8);
    }
    float l1f[16];
    {
        const unsigned short* hr = catHL + (size_t)hcol*256;
        const unsigned short* lr = hr + 128;
        const ushort4 h0 = *(const ushort4*)(hr + lg*8);
        const ushort4 h1 = *(const ushort4*)(hr + lg*8 + 4);
        const ushort4 h2 = *(const ushort4*)(hr + 32 + lg*8);
        const ushort4 h3 = *(const ushort4*)(hr + 32 + lg*8 + 4);
        const ushort4 l0 = *(const ushort4*)(lr + lg*8);
        const ushort4 l1 = *(const ushort4*)(lr + lg*8 + 4);
        const ushort4 l2 = *(const ushort4*)(lr + 32 + lg*8);
        const ushort4 l3 = *(const ushort4*)(lr + 32 + lg*8 + 4);
        l1f[0]=bf2f(h0.x,l0.x); l1f[1]=bf2f(h0.y,l0.y); l1f[2]=bf2f(h0.z,l0.z); l1f[3]=bf2f(h0.w,l0.w);
        l1f[4]=bf2f(h1.x,l1.x); l1f[5]=bf2f(h1.y,l1.y); l1f[6]=bf2f(h1.z,l1.z); l1f[7]=bf2f(h1.w,l1.w);
        l1f[8]=bf2f(h2.x,l2.x); l1f[9]=bf2f(h2.y,l2.y); l1f[10]=bf2f(h2.z,l2.z); l1f[11]=bf2f(h2.w,l2.w);
        l1f[12]=bf2f(h3.x,l3.x); l1f[13]=bf2f(h3.y,l3.y); l1f[14]=bf2f(h3.z,l3.z); l1f[15]=bf2f(h3.w,l3.w);
    }
    float cb1r[8], cb2r[8];
    #pragma unroll
    for (int i=0;i<8;++i){
        cb1r[i] = cb1[(i>>2)*16 + lg*4 + (i&3)];
        cb2r[i] = cb2[(i>>2)*16 + lg*4 + (i&3)];
    }
    float agg[8] = {};
    const f32x4 z = {0.f,0.f,0.f,0.f};

    const int kbeg = w*8;
    int idx0 = ci[(kbeg+0)*HL + hcol];
    int idx1 = ci[(kbeg+1)*HL + hcol];
    uint4 GaL,GaH, GbL,GbH;
    {
        const unsigned short* r = lat2b + (size_t)idx0*64 + lg*8;
        GaL = *(const uint4*)r;  GaH = *(const uint4*)(r + 32);
    }
    {
        const unsigned short* r = lat2b + (size_t)idx1*64 + lg*8;
        GbL = *(const uint4*)r;  GbH = *(const uint4*)(r + 32);
    }
    idx0 = ci[(kbeg+2)*HL + hcol];
    idx1 = ci[(kbeg+3)*HL + hcol];
    #pragma unroll 1
    for (int k2=0; k2<4; ++k2){
        const int ke = kbeg + 2*k2;
        corr_step(GaL,GaH, idx0, min(ke+4, 31), lat2b, ci, hcol, lg,
                  l1f, cb1r, cb2r, C1H, C1L, C2H, C2L, sel, srcA, srcB, agg);
        corr_step(GbL,GbH, idx1, min(ke+5, 31), lat2b, ci, hcol, lg,
                  l1f, cb1r, cb2r, C1H, C1L, C2H, C2L, sel, srcA, srcB, agg);
    }
    if (w){
        #pragma unroll
        for (int i=0;i<8;++i) AGG[w-1][lane][i] = agg[i];
    }
    __syncthreads();
    if (w) return;
    #pragma unroll
    for (int i=0;i<8;++i)
        agg[i] = (agg[i] + AGG[0][lane][i] + AGG[1][lane][i] + AGG[2][lane][i]) * (1.0f/32.0f);
    unsigned agH[2][2], agL[2][2];
    #pragma unroll
    for (int ot=0; ot<2; ++ot)
        #pragma unroll
        for (int j=0; j<2; ++j)
            fsplit2(agg[ot*4+2*j], agg[ot*4+2*j+1], agH[ot][j], agL[ot][j]);
    pk8 B3H = shuf32(agH[0], agH[1], sel, srcA, srcB);
    pk8 B3L = shuf32(agL[0], agL[1], sel, srcA, srcB);
    float db1r[16], db2r[16];
    #pragma unroll
    for (int i=0;i<16;++i){
        db1r[i] = db1[(i>>2)*16 + lg*4 + (i&3)];
        db2r[i] = db2[(i>>2)*16 + lg*4 + (i&3)];
    }
    unsigned d1H[4][2], d1L[4][2];
    #pragma unroll
    for (int ot=0; ot<4; ++ot){
        s16x8 AH = *(const s16x8*)(W16 + 6144 + ot*512 + lane*8);
        s16x8 AL = *(const s16x8*)(W16 + 8192 + ot*512 + lane*8);
        f32x4 a3 = z;
        a3 = __builtin_amdgcn_mfma_f32_16x16x32_bf16(AH, B3H.v, a3, 0,0,0);
        a3 = __builtin_amdgcn_mfma_f32_16x16x32_bf16(AH, B3L.v, a3, 0,0,0);
        a3 = __builtin_amdgcn_mfma_f32_16x16x32_bf16(AL, B3H.v, a3, 0,0,0);
        #pragma unroll
        for (int j=0;j<2;++j)
            fsplit2(lrelu(a3[2*j]   + db1r[ot*4+2*j]),
                    lrelu(a3[2*j+1] + db1r[ot*4+2*j+1]), d1H[ot][j], d1L[ot][j]);
    }
    f32x4 a4[4] = {z,z,z,z};
    #pragma unroll
    for (int kt=0; kt<2; ++kt){
        pk8 B4H = shuf32(d1H[kt*2], d1H[kt*2+1], sel, srcA, srcB);
        pk8 B4L = shuf32(d1L[kt*2], d1L[kt*2+1], sel, srcA, srcB);
        #pragma unroll
        for (int ot=0; ot<4; ++ot){
            s16x8 AH = *(const s16x8*)(W16 + 10240 + (ot*2+kt)*512 + lane*8);
            s16x8 AL = *(const s16x8*)(W16 + 14336 + (ot*2+kt)*512 + lane*8);
            a4[ot] = __builtin_amdgcn_mfma_f32_16x16x32_bf16(AH, B4H.v, a4[ot], 0,0,0);
            a4[ot] = __builtin_amdgcn_mfma_f32_16x16x32_bf16(AH, B4L.v, a4[ot], 0,0,0);
            a4[ot] = __builtin_amdgcn_mfma_f32_16x16x32_bf16(AL, B4H.v, a4[ot], 0,0,0);
        }
    }
    unsigned short* dH = catHL + (size_t)hcol*256 + 64;
    unsigned short* dL = catHL + (size_t)hcol*256 + 192;
    #pragma unroll
    for (int ot=0; ot<4; ++ot){
        float v0 = lrelu(a4[ot][0]+db2r[ot*4+0]), v1 = lrelu(a4[ot][1]+db2r[ot*4+1]);
        float v2 = lrelu(a4[ot][2]+db2r[ot*4+2]), v3 = lrelu(a4[ot][3]+db2r[ot*4+3]);
        unsigned short th[4], tl[4];
        fsplit1(v0, th[0], tl[0]); fsplit1(v1, th[1], tl[1]);
        fsplit1(v2, th[2], tl[2]); fsplit1(v3, th[3], tl[3]);
        *(ushort4*)(dH + ot*16 + lg*4) = make_ushort4(th[0],th[1],th[2],th[3]);
        *(ushort4*)(dL + ot*16 + lg*4) = make_ushort4(tl[0],tl[1],tl[2],tl[3]);
    }
}

// ---------------------------------------------------------------- blur_p: async global_load_lds staging (swizzled source, linear LDS)
__global__ __launch_bounds__(512) void blur_p_mfma_kernel(
        const unsigned short* __restrict__ catHL,
        const int* __restrict__ nb,
        const unsigned short* __restrict__ pw1fH, const unsigned short* __restrict__ pw1fL,
        const float* __restrict__ pb1,
        const unsigned short* __restrict__ pw2fH, const unsigned short* __restrict__ pw2fL,
        const float* __restrict__ pb2,
        unsigned short* __restrict__ p16){
    __shared__ __align__(16) unsigned short GH[2][4096];
    __shared__ int sidx[NNB][32];
    const int t = threadIdx.x;
    const int hb = blockIdx.x*32;
    const int w = t>>6, lane = t&63;
    const int l15 = lane&15, lg = lane>>4;
    const int row = t>>4, q = t&15;
    const int srcOff = (q ^ (row&7))*8;       // swizzle applied at the SOURCE
    for (int e=t; e<NNB*32; e+=512) sidx[e>>5][e&31] = nb[(e>>5)*HL + hb + (e&31)];
    const f32x4 z = {0.f,0.f,0.f,0.f};
    f32x4 acc1[2] = {z,z};
    __syncthreads();
#define PSTAGE(NN_,BUF_) { \
        const int g_ = sidx[NN_][row]; \
        async_cp16(catHL + (size_t)g_*256 + srcOff, GH[BUF_] + w*512); }
#define PCOMPUTE(NN_,BUF_) { \
        _Pragma("unroll") \
        for (int kt=0; kt<4; ++kt){ \
            s16x8 BH[2]; \
            _Pragma("unroll") \
            for (int ht=0; ht<2; ++ht){ \
                const int h_ = ht*16 + l15; \
                const int qq_ = kt*4 + lg; \
                const int d_ = h_*128 + ((qq_ ^ (h_&7))*8); \
                BH[ht] = *(const s16x8*)(GH[BUF_] + d_); } \
            const size_t fo_ = ((size_t)(((NN_)*4 + kt)*8 + w))*512 + lane*8; \
            const s16x8 AH = *(const s16x8*)(pw1fH + fo_); \
            const s16x8 AL = *(const s16x8*)(pw1fL + fo_); \
            _Pragma("unroll") \
            for (int ht=0; ht<2; ++ht){ \
                acc1[ht] = __builtin_amdgcn_mfma_f32_16x16x32_bf16(AH, BH[ht], acc1[ht], 0,0,0); \
                acc1[ht] = __builtin_amdgcn_mfma_f32_16x16x32_bf16(AL, BH[ht], acc1[ht], 0,0,0); } } }
    PSTAGE(0,0)
    __syncthreads();
    #pragma unroll 1
    for (int nn=0; nn<NNB; ++nn){
        const int cur = nn&1;
        if (nn+1 < NNB) PSTAGE((nn+1),(cur^1))
        PCOMPUTE(nn,cur)
        __syncthreads();
    }
#undef PSTAGE
#undef PCOMPUTE
    // epilogue 1: T = lrelu(acc1 + pb1); hi -> GH[0], lo -> GH[1]
    {
        const int o0 = w*16 + lg*4;
        const float b0 = pb1[o0], b1v = pb1[o0+1], b2v = pb1[o0+2], b3v = pb1[o0+3];
        const int qc = o0>>3;
        #pragma unroll
        for (int ht=0; ht<2; ++ht){
            const int h = ht*16 + l15;
            unsigned short th[4], tl[4];
            bf16_hilo(lrelu(acc1[ht][0] + b0), th[0], tl[0]);
            bf16_hilo(lrelu(acc1[ht][1] + b1v), th[1], tl[1]);
            bf16_hilo(lrelu(acc1[ht][2] + b2v), th[2], tl[2]);
            bf16_hilo(lrelu(acc1[ht][3] + b3v), th[3], tl[3]);
            const int d = h*128 + ((qc ^ (h&7))*8) + (o0&7);
            *(ushort4*)(GH[0] + d) = make_ushort4(th[0],th[1],th[2],th[3]);
            *(ushort4*)(GH[1] + d) = make_ushort4(tl[0],tl[1],tl[2],tl[3]);
        }
    }
    __syncthreads();
    f32x4 acc2[2] = {z,z};
    #pragma unroll
    for (int kt=0; kt<4; ++kt){
        s16x8 BH[2], BL[2];
        #pragma unroll
        for (int ht=0; ht<2; ++ht){
            const int h = ht*16 + l15;
            const int qq = kt*4 + lg;
            const int d = h*128 + ((qq ^ (h&7))*8);
            BH[ht] = *(const s16x8*)(GH[0] + d);
            BL[ht] = *(const s16x8*)(GH[1] + d);
        }
        const size_t fo = ((size_t)(kt*8 + w))*512 + lane*8;
        const s16x8 AH = *(const s16x8*)(pw2fH + fo);
        const s16x8 AL = *(const s16x8*)(pw2fL + fo);
        #pragma unroll
        for (int ht=0; ht<2; ++ht){
            acc2[ht] = __builtin_amdgcn_mfma_f32_16x16x32_bf16(AH, BH[ht], acc2[ht], 0,0,0);
            acc2[ht] = __builtin_amdgcn_mfma_f32_16x16x32_bf16(AH, BL[ht], acc2[ht], 0,0,0);
            acc2[ht] = __builtin_amdgcn_mfma_f32_16x16x32_bf16(AL, BH[ht], acc2[ht], 0,0,0);
        }
    }
    {
        const int o0 = w*16 + lg*4;
        const float b0 = pb2[o0], b1v = pb2[o0+1], b2v = pb2[o0+2], b3v = pb2[o0+3];
        #pragma unroll
        for (int ht=0; ht<2; ++ht){
            const int h = hb + ht*16 + l15;
            *(ushort4*)(p16 + (size_t)h*128 + o0) = make_ushort4(
                bf16r(lrelu(acc2[ht][0] + b0)),  bf16r(lrelu(acc2[ht][1] + b1v)),
                bf16r(lrelu(acc2[ht][2] + b2v)), bf16r(lrelu(acc2[ht][3] + b3v)));
        }
    }
}

// ---------------------------------------------------------------- head: slice (bf16 p) + 128->128->64->3
__global__ __launch_bounds__(256) void head_kernel(
        const unsigned short* __restrict__ p16, const float* __restrict__ bary, const int* __restrict__ off,
        const float* __restrict__ fw2T, const float* __restrict__ fb2,
        const float* __restrict__ fw3T, const float* __restrict__ fb3,
        const float* __restrict__ fw4, const float* __restrict__ fb4,
        float* __restrict__ out){
    __shared__ __align__(16) float S[8704];
    __shared__ __align__(16) float WW[8192];
    __shared__ float SB[5][64];
    __shared__ int   SO[5][64];
    const int t = threadIdx.x;
    const int pb = blockIdx.x*64;
    const int oq8 = t>>4, pq = t&15;
    if (t<64){
        #pragma unroll
        for (int j=0;j<5;++j){ SB[j][t]=bary[j*NPTS+pb+t]; SO[j][t]=off[j*NPTS+pb+t]; }
    }
    __syncthreads();
    // stage S[c][pt]: 16 threads/row x 8 ch, 4 row-passes
    {
        const int qh = t & 15, rg = t >> 4;
        #pragma unroll
        for (int i=0;i<4;++i){
            const int row = rg + 16*i;
            float sa[8] = {0.f,0.f,0.f,0.f,0.f,0.f,0.f,0.f};
            #pragma unroll
            for (int j=0;j<5;++j){
                const uint4 v = *(const uint4*)(p16 + (size_t)SO[j][row]*128 + qh*8);
                const float b = SB[j][row];
                sa[0]+=b*blo(v.x); sa[1]+=b*bhi(v.x);
                sa[2]+=b*blo(v.y); sa[3]+=b*bhi(v.y);
                sa[4]+=b*blo(v.z); sa[5]+=b*bhi(v.z);
                sa[6]+=b*blo(v.w); sa[7]+=b*bhi(v.w);
            }
            #pragma unroll
            for (int c=0;c<8;++c) S[(qh*8+c)*68 + row] = sa[c];
        }
    }
    float acc1[8][4] = {};
    #pragma unroll 1
    for (int hf=0;hf<2;++hf){
        if (hf==1) __syncthreads();
        for (int e=t;e<2048;e+=256)
            *(float4*)(WW + e*4) = *(const float4*)(fw2T + hf*8192 + e*4);
        __syncthreads();
        #pragma unroll 4
        for (int c=0;c<64;++c){
            const float4 a4 = *(const float4*)(S + (hf*64+c)*68 + pq*4);
            const float4 wa = *(const float4*)(WW + c*128 + oq8*8);
            const float4 wb = *(const float4*)(WW + c*128 + oq8*8 + 4);
            const float av[4]={a4.x,a4.y,a4.z,a4.w};
            const float wv[8]={wa.x,wa.y,wa.z,wa.w,wb.x,wb.y,wb.z,wb.w};
            #pragma unroll
            for (int i=0;i<8;++i)
                #pragma unroll
                for (int j=0;j<4;++j)
                    acc1[i][j] = fmaf(wv[i], av[j], acc1[i][j]);
        }
    }
    __syncthreads();
    float bf2v[8];
    #pragma unroll
    for (int i=0;i<8;++i) bf2v[i]=fb2[oq8*8+i];
    #pragma unroll
    for (int i=0;i<8;++i){
        const int o = oq8*8+i;
        float4 v = make_float4(lrelu(acc1[i][0]+bf2v[i]), lrelu(acc1[i][1]+bf2v[i]),
                               lrelu(acc1[i][2]+bf2v[i]), lrelu(acc1[i][3]+bf2v[i]));
        *(float4*)(S + o*68 + pq*4) = v;
    }
    for (int e=t;e<2048;e+=256)
        *(float4*)(WW + e*4) = *(const float4*)(fw3T + e*4);
    __syncthreads();
    const int od = t>>4;
    float bf3[4];
    #pragma unroll
    for (int i=0;i<4;++i) bf3[i]=fb3[od*4+i];
    float a2[4][4] = {};
    #pragma unroll 4
    for (int c=0;c<128;++c){
        const float4 a4 = *(const float4*)(S + c*68 + pq*4);
        const float4 w4 = *(const float4*)(WW + c*64 + od*4);
        const float av[4]={a4.x,a4.y,a4.z,a4.w};
        const float wv[4]={w4.x,w4.y,w4.z,w4.w};
        #pragma unroll
        for (int i=0;i<4;++i)
            #pragma unroll
            for (int j=0;j<4;++j)
                a2[i][j] = fmaf(wv[i], av[j], a2[i][j]);
    }
    __syncthreads();
    #pragma unroll
    for (int i=0;i<4;++i){
        float4 v = make_float4(lrelu(a2[i][0]+bf3[i]), lrelu(a2[i][1]+bf3[i]),
                               lrelu(a2[i][2]+bf3[i]), lrelu(a2[i][3]+bf3[i]));
        *(float4*)(S + (od*4+i)*68 + pq*4) = v;
    }
    __syncthreads();
    if (t < 192){
        const int r = t>>6, pp = t&63;
        float a = fb4[r];
        #pragma unroll 8
        for (int c=0;c<64;++c) a += fw4[r*64+c]*S[c*68+pp];
        out[r*NPTS + pb + pp] = a;
    }
}

// ================================================================ launch
extern "C" void kernel_launch(void* const* d_in, const int* in_sizes, int n_in,
                              void* d_out, int out_size, void* d_ws, size_t ws_size,
                              hipStream_t stream){
    const float* pc1   = (const float*)d_in[0];
    const float* pc2   = (const float*)d_in[1];
    const float* el1   = (const float*)d_in[2];
    const float* el2   = (const float*)d_in[3];
    const float* bary1 = (const float*)d_in[4];
    const float* bary2 = (const float*)d_in[5];
    const int*   off1  = (const int*)d_in[6];
    const int*   off2  = (const int*)d_in[7];
    const int*   nb1   = (const int*)d_in[8];
    const int*   nb2   = (const int*)d_in[9];
    const int*   ci    = (const int*)d_in[10];
    const float* w1    = (const float*)d_in[11];
    const float* b1    = (const float*)d_in[12];
    const float* w2    = (const float*)d_in[13];
    const float* b2    = (const float*)d_in[14];
    const float* w3    = (const float*)d_in[15];
    const float* b3    = (const float*)d_in[16];
    const float* sw1   = (const float*)d_in[17];
    const float* sb1   = (const float*)d_in[18];
    const float* sw2   = (const float*)d_in[19];
    const float* sb2   = (const float*)d_in[20];
    const float* cw1   = (const float*)d_in[21];
    const float* cb1   = (const float*)d_in[22];
    const float* cw2   = (const float*)d_in[23];
    const float* cb2   = (const float*)d_in[24];
    const float* dw1   = (const float*)d_in[25];
    const float* db1   = (const float*)d_in[26];
    const float* dw2   = (const float*)d_in[27];
    const float* db2   = (const float*)d_in[28];
    const float* pw1   = (const float*)d_in[29];
    const float* pb1   = (const float*)d_in[30];
    const float* pw2   = (const float*)d_in[31];
    const float* pb2   = (const float*)d_in[32];
    const float* fw2   = (const float*)d_in[33];
    const float* fb2   = (const float*)d_in[34];
    const float* fw3   = (const float*)d_in[35];
    const float* fb3   = (const float*)d_in[36];
    const float* fw4   = (const float*)d_in[37];
    const float* fb4   = (const float*)d_in[38];
    float* out = (float*)d_out;

    float* ws    = (float*)d_ws;
    float* pf1f  = ws;                    // 2228224 floats region ; pfeat bf16 + later p16
    float* pf2f  = pf1f  + 2228224;
    float* bkt   = pf2f  + 2228224;       // 4456448 (buckets) ; later catHL
    float* lat16 = bkt   + 4456448;       // compact hi lattice: 2*HL*72 ushorts
    float* lat2f = lat16 + 4456448;       // lat2b bf16 (HL*64 ushorts)
    float* pw1fS = lat2f + 2097152;       // 245760
    float* SW16f = pw1fS + 245760;        // 69632
    float* W16f  = SW16f + 69632;         // 9216
    float* pw2fS = W16f  + 9216;          // 16384
    float* fw2T  = pw2fS + 16384;         // 16384
    float* fw3T  = fw2T  + 16384;         // 8192
    float* cntf  = fw3T  + 8192;          // 16384 ints

    unsigned short* pw1fH = (unsigned short*)pw1fS;
    unsigned short* pw1fL = pw1fH + 245760;
    unsigned short* SW16  = (unsigned short*)SW16f;
    unsigned short* W16   = (unsigned short*)W16f;
    unsigned short* pw2fH = (unsigned short*)pw2fS;
    unsigned short* pw2fL = pw2fH + 16384;
    int*   cnt  = (int*)cntf;
    int*   bnA  = (int*)bkt;
    float* bvA  = bkt + (size_t)HL*BCAP;
    int*   bnB  = (int*)(bkt + 2228224);
    float* bvB  = bkt + 2228224 + (size_t)HL*BCAP;
    unsigned short* pf1 = (unsigned short*)pf1f;         // NPTS*72 bf16
    unsigned short* pf2 = (unsigned short*)pf2f;
    unsigned short* latA16 = (unsigned short*)lat16;     // HL*72 compact hi
    unsigned short* latB16 = latA16 + (size_t)HL*72;
    unsigned short* catHL  = (unsigned short*)bkt;       // HL*256 (buckets dead)
    unsigned short* lat2b  = (unsigned short*)lat2f;     // HL*64 bf16-hi
    unsigned short* p16    = (unsigned short*)pf1f;      // HL*128 bf16 (pfeat dead)

    init_kernel<<<960, 256, 0, stream>>>(cnt,
                                         sw1, pw1, sw2, cw1, cw2, dw1, dw2, pw2, fw2, fw3,
                                         SW16, pw1fH, pw1fL, W16,
                                         pw2fH, pw2fL, fw2T, fw3T);

    mlp3_kernel<<<256, 256, 0, stream>>>(pc1, el1, pc2, el2, w1,b1,w2,b2,w3,b3, pf1, pf2);

    bucket_kernel<<<1280, 256, 0, stream>>>(bary1, bary2, off1, off2, cnt,
                                            bnA, bvA, bnB, bvB);

    splat2_kernel<<<16384, 256, 0, stream>>>(pf1, pf2, cnt, bnA, bvA, bnB, bvB,
                                             latA16, latB16);

    blur_s_mfma_kernel<<<2048, 256, 0, stream>>>(latA16, latB16, nb1, nb2, SW16, sb1, sb2,
                                                 lat2b, catHL);

    corr_mfma_kernel<<<2048, 256, 0, stream>>>(lat2b, ci, W16, cb1, cb2, db1, db2, catHL);

    blur_p_mfma_kernel<<<1024, 512, 0, stream>>>(catHL, nb1, pw1fH, pw1fL, pb1,
                                                 pw2fH, pw2fL, pb2, p16);

    head_kernel<<<512, 256, 0, stream>>>(p16, bary1, off1, fw2T,fb2,fw3T,fb3,fw4,fb4, out);
}

// Round 23
// 262.016 us; speedup vs baseline: 1.4031x; 1.4031x over previous
//
#include <hip/hip_runtime.h>

#define NPTS 32768
#define HL   32768
#define NNB  15
#define KC   32
#define BCAP 32

typedef __attribute__((ext_vector_type(8))) short s16x8;
typedef __attribute__((ext_vector_type(4))) float f32x4;

typedef union { s16x8 v; unsigned u[4]; } pk8;

__device__ __forceinline__ float lrelu(float x){ return x > 0.0f ? x : 0.1f*x; }

__device__ __forceinline__ unsigned short bf16r(float x){
    union { float f; unsigned u; } a; a.f = x;
    unsigned r = a.u + 0x7FFF + ((a.u >> 16) & 1);
    return (unsigned short)(r >> 16);
}
__device__ __forceinline__ void bf16_hilo(float x, unsigned short& hi, unsigned short& lo){
    hi = bf16r(x);
    union { float f; unsigned u; } b; b.u = ((unsigned)hi) << 16;
    lo = bf16r(x - b.f);
}
__device__ __forceinline__ void fsplit2(float a, float b, unsigned &h, unsigned &l){
    unsigned ua = __float_as_uint(a), ub = __float_as_uint(b);
    unsigned ha = ua & 0xFFFF0000u, hb = ub & 0xFFFF0000u;
    float ra = a - __uint_as_float(ha);
    float rb = b - __uint_as_float(hb);
    h = (ha >> 16) | hb;
    l = (__float_as_uint(ra) >> 16) | (__float_as_uint(rb) & 0xFFFF0000u);
}
__device__ __forceinline__ void fsplit1(float a, unsigned short &h, unsigned short &l){
    unsigned ua = __float_as_uint(a);
    unsigned ha = ua & 0xFFFF0000u;
    float ra = a - __uint_as_float(ha);
    h = (unsigned short)(ua >> 16);
    l = (unsigned short)(__float_as_uint(ra) >> 16);
}
__device__ __forceinline__ float bf2f(unsigned short h, unsigned short l){
    return __uint_as_float(((unsigned)h)<<16) + __uint_as_float(((unsigned)l)<<16);
}
__device__ __forceinline__ float blo(unsigned u){ return __uint_as_float(u << 16); }
__device__ __forceinline__ float bhi(unsigned u){ return __uint_as_float(u & 0xFFFF0000u); }
__device__ __forceinline__ float us2f(unsigned short u){ return __uint_as_float(((unsigned)u)<<16); }

__device__ __forceinline__ void async_cp16(const unsigned short* g, unsigned short* l){
    __builtin_amdgcn_global_load_lds(
        (const __attribute__((address_space(1))) unsigned int*)g,
        (__attribute__((address_space(3))) unsigned int*)l,
        16, 0, 0);
}

__device__ __forceinline__ pk8 shuf32(const unsigned* p0, const unsigned* p1,
                                      int sel, int srcA, int srcB){
    pk8 o;
    int a0 = __builtin_amdgcn_ds_bpermute(srcA, (int)p0[0]);
    int a1 = __builtin_amdgcn_ds_bpermute(srcA, (int)p1[0]);
    o.u[0] = (unsigned)(sel ? a1 : a0);
    int b0 = __builtin_amdgcn_ds_bpermute(srcA, (int)p0[1]);
    int b1 = __builtin_amdgcn_ds_bpermute(srcA, (int)p1[1]);
    o.u[1] = (unsigned)(sel ? b1 : b0);
    int c0 = __builtin_amdgcn_ds_bpermute(srcB, (int)p0[0]);
    int c1 = __builtin_amdgcn_ds_bpermute(srcB, (int)p1[0]);
    o.u[2] = (unsigned)(sel ? c1 : c0);
    int d0 = __builtin_amdgcn_ds_bpermute(srcB, (int)p0[1]);
    int d1 = __builtin_amdgcn_ds_bpermute(srcB, (int)p1[1]);
    o.u[3] = (unsigned)(sel ? d1 : d0);
    return o;
}

// ---------------------------------------------------------------- init: zero counters + repack weights
__global__ void init_kernel(int* __restrict__ cnt,
                              const float* __restrict__ sw1, const float* __restrict__ pw1,
                              const float* __restrict__ sw2, const float* __restrict__ cw1,
                              const float* __restrict__ cw2, const float* __restrict__ dw1,
                              const float* __restrict__ dw2, const float* __restrict__ pw2,
                              const float* __restrict__ fw2, const float* __restrict__ fw3,
                              unsigned short* __restrict__ SW16,
                              unsigned short* __restrict__ pw1fH, unsigned short* __restrict__ pw1fL,
                              unsigned short* __restrict__ W16,
                              unsigned short* __restrict__ pw2fH, unsigned short* __restrict__ pw2fL,
                              float* __restrict__ fw2T, float* __restrict__ fw3T){
    int tid = blockIdx.x*256 + threadIdx.x;
    if (tid < 2*HL) cnt[tid] = 0;
    if (tid < 61440){
        int b = tid&7, ln = (tid>>3)&63, ot = (tid>>9)&3, f = tid>>11;
        int kt = f&1, nn = f>>1;
        int o = ot*16 + (ln&15), k = kt*32 + (ln>>4)*8 + b, c = k + 4;
        unsigned short hi, lo; bf16_hilo(sw1[(o*68+c)*15+nn], hi, lo);
        SW16[tid] = hi; SW16[61440+tid] = lo;
    }
    if (tid < 4096){
        int b = tid&7, ln = (tid>>3)&63, ot = (tid>>9)&3, kt2 = tid>>11;
        int o = ot*16 + (ln&15), k2 = kt2*32 + (ln>>4)*8 + b;
        float v = (k2 < 60) ? sw1[(o*68 + (k2&3))*15 + (k2>>2)] : 0.f;
        unsigned short hi, lo; bf16_hilo(v, hi, lo);
        SW16[122880+tid] = hi; SW16[126976+tid] = lo;
    }
    if (tid < 4096){
        int b = tid&7, ln = (tid>>3)&63, ot = (tid>>9)&3, kt = tid>>11;
        int o = ot*16 + (ln&15), k = kt*32 + (ln>>4)*8 + b;
        unsigned short hi, lo; bf16_hilo(sw2[o*64+k], hi, lo);
        SW16[131072+tid] = hi; SW16[135168+tid] = lo;
    }
    if (tid < 245760){
        int b = tid & 7, ln = (tid>>3)&63, ot = (tid>>9)&7, kt = (tid>>12)&3, nn = tid>>14;
        int o = ot*16 + (ln&15), k = kt*32 + (ln>>4)*8 + b;
        float v = pw1[(o*128 + k)*15 + nn];
        unsigned short hi, lo; bf16_hilo(v, hi, lo);
        pw1fH[tid] = hi; pw1fL[tid] = lo;
    }
    if (tid < 16384){
        int b = tid & 7, ln = (tid>>3)&63, ot = (tid>>9)&7, kt = (tid>>12)&3;
        int o = ot*16 + (ln&15), k = kt*32 + (ln>>4)*8 + b;
        float v = pw2[o*128 + k];
        unsigned short hi, lo; bf16_hilo(v, hi, lo);
        pw2fH[tid] = hi; pw2fL[tid] = lo;
    }
    if (tid < 2048){
        int b = tid&7, ln = (tid>>3)&63, f = tid>>9;
        int ot = f>>1, kt = f&1;
        int o = ot*16 + (ln&15), c = kt*32 + (ln>>4)*8 + b;
        unsigned short hi, lo; bf16_hilo(cw1[o*64+c], hi, lo);
        W16[tid] = hi; W16[2048+tid] = lo;
    }
    if (tid < 1024){
        int b = tid&7, ln = (tid>>3)&63, ot = tid>>9;
        int o = ot*16 + (ln&15), c = (ln>>4)*8 + b;
        unsigned short hi, lo; bf16_hilo(cw2[o*32+c], hi, lo);
        W16[4096+tid] = hi; W16[5120+tid] = lo;
    }
    if (tid < 2048){
        int b = tid&7, ln = (tid>>3)&63, ot = tid>>9;
        int o = ot*16 + (ln&15), c = (ln>>4)*8 + b;
        unsigned short hi, lo; bf16_hilo(dw1[o*32+c], hi, lo);
        W16[6144+tid] = hi; W16[8192+tid] = lo;
    }
    if (tid < 4096){
        int b = tid&7, ln = (tid>>3)&63, f = tid>>9;
        int ot = f>>1, kt = f&1;
        int o = ot*16 + (ln&15), c = kt*32 + (ln>>4)*8 + b;
        unsigned short hi, lo; bf16_hilo(dw2[o*64+c], hi, lo);
        W16[10240+tid] = hi; W16[14336+tid] = lo;
    }
    if (tid < 16384){ int c = tid>>7, o = tid&127; fw2T[tid] = fw2[o*128+c]; }
    if (tid < 8192){ int c = tid>>6, o = tid&63; fw3T[tid] = fw3[o*128+c]; }
}

// ---------------------------------------------------------------- point MLP (both clouds) -> bf16 rows [el4][feat64][pad4]
__global__ __launch_bounds__(256) void mlp3_kernel(
        const float* __restrict__ pc1, const float* __restrict__ el1,
        const float* __restrict__ pc2, const float* __restrict__ el2,
        const float* __restrict__ w1, const float* __restrict__ b1,
        const float* __restrict__ w2, const float* __restrict__ b2,
        const float* __restrict__ w3, const float* __restrict__ b3,
        unsigned short* __restrict__ pf1, unsigned short* __restrict__ pf2){
    __shared__ float W1[96], W2s[1024], W3s[2048], B1[32], B2[32], B3[64];
    const int t = threadIdx.x;
    const int side = (int)(blockIdx.x >= 128);
    const float* pc = side ? pc2 : pc1;
    const float* el = side ? el2 : el1;
    unsigned short* pfeat = side ? pf2 : pf1;
    for (int e=t;e<96;e+=256)   W1[e]=w1[e];
    for (int e=t;e<1024;e+=256) W2s[e]=w2[e];
    for (int e=t;e<2048;e+=256) W3s[e]=w3[e];
    if (t<32){ B1[t]=b1[t]; B2[t]=b2[t]; }
    if (t<64){ B3[t]=b3[t]; }
    __syncthreads();
    const int n = (blockIdx.x & 127)*256 + t;
    const float x0 = pc[n], x1 = pc[NPTS+n], x2 = pc[2*NPTS+n];
    float h1[32];
    #pragma unroll
    for (int o=0;o<32;++o)
        h1[o] = lrelu(B1[o] + W1[o*3]*x0 + W1[o*3+1]*x1 + W1[o*3+2]*x2);
    float h2[32];
    #pragma unroll
    for (int o=0;o<32;++o){
        float a = B2[o];
        #pragma unroll
        for (int c=0;c<32;++c) a += W2s[o*32+c]*h1[c];
        h2[o] = lrelu(a);
    }
    unsigned short* row = pfeat + (size_t)n*72;
    *(ushort4*)row = make_ushort4(bf16r(el[n]), bf16r(el[NPTS+n]),
                                  bf16r(el[2*NPTS+n]), bf16r(el[3*NPTS+n]));
    #pragma unroll
    for (int o4=0;o4<16;++o4){
        float tmp[4];
        #pragma unroll
        for (int q=0;q<4;++q){
            const int o = o4*4+q;
            float a = B3[o];
            #pragma unroll
            for (int c=0;c<32;++c) a += W3s[o*32+c]*h2[c];
            tmp[q] = lrelu(a);
        }
        *(ushort4*)(row + 4 + o4*4) = make_ushort4(bf16r(tmp[0]), bf16r(tmp[1]),
                                                   bf16r(tmp[2]), bf16r(tmp[3]));
    }
    *(ushort4*)(row + 68) = make_ushort4(0,0,0,0);
}

// ---------------------------------------------------------------- bucket build (inverse map)
__global__ __launch_bounds__(256) void bucket_kernel(
        const float* __restrict__ bary1, const float* __restrict__ bary2,
        const int* __restrict__ off1, const int* __restrict__ off2,
        int* __restrict__ cnt,
        int* __restrict__ bnA, float* __restrict__ bvA,
        int* __restrict__ bnB, float* __restrict__ bvB){
    const int tid = blockIdx.x*256 + threadIdx.x;
    const int side = (int)(tid >= 5*NPTS);
    const int p = tid - side*5*NPTS;
    const float b = side ? bary2[p] : bary1[p];
    const int h = side ? off2[p] : off1[p];
    int* bn = side ? bnB : bnA;
    float* bv = side ? bvB : bvA;
    const int slot = atomicAdd(&cnt[side*HL + h], 1);
    if (slot < BCAP){
        bn[h*BCAP + slot] = p & (NPTS-1);
        bv[h*BCAP + slot] = b;
    }
}

// ---------------------------------------------------------------- splat2: gather bf16 pfeat rows -> compact bf16-hi lattice
// lattice row (72 ushorts): [featH 64][elH 4][pad 4]
__global__ __launch_bounds__(256) void splat2_kernel(
        const unsigned short* __restrict__ pf1, const unsigned short* __restrict__ pf2,
        const int* __restrict__ cnt,
        const int* __restrict__ bnA, const float* __restrict__ bvA,
        const int* __restrict__ bnB, const float* __restrict__ bvB,
        unsigned short* __restrict__ latA16, unsigned short* __restrict__ latB16){
    const int gw = (blockIdx.x*256 + threadIdx.x) >> 6;
    const int lane = threadIdx.x & 63;
    const int side = (int)(gw >= HL);
    const int h = gw - side*HL;
    const unsigned short* pfeat = side ? pf2 : pf1;
    const int* bn = side ? bnB : bnA;
    const float* bv = side ? bvB : bvA;
    unsigned short* lat = side ? latB16 : latA16;
    int c = cnt[side*HL + h]; if (c > BCAP) c = BCAP;
    float accF = 0.f, accE = 0.f;
    if (c > 0){
        int n = bn[h*BCAP];
        float b = bv[h*BCAP];
        for (int i=0; i<c; ++i){
            int n2 = 0; float b2 = 0.f;
            if (i+1 < c){ n2 = bn[h*BCAP+i+1]; b2 = bv[h*BCAP+i+1]; }
            const unsigned short* row = pfeat + (size_t)n*72;
            accF += b * us2f(row[4+lane]);
            if (lane < 4) accE += b * us2f(row[lane]);
            n = n2; b = b2;
        }
    }
    lat[(size_t)h*72 + lane] = bf16r(accF);
    if (lane < 4) lat[(size_t)h*72 + 64 + lane] = bf16r(accE);
    if (lane >= 60 && lane < 64) lat[(size_t)h*72 + 8 + lane] = 0;   // pad 68..71
}

// ---------------------------------------------------------------- blur_s: async global_load_lds feat staging (swizzled source), reg-staged el
__global__ __launch_bounds__(256) void blur_s_mfma_kernel(
        const unsigned short* __restrict__ latA16, const unsigned short* __restrict__ latB16,
        const int* __restrict__ nb1, const int* __restrict__ nb2,
        const unsigned short* __restrict__ SW16,
        const float* __restrict__ sb1, const float* __restrict__ sb2,
        unsigned short* __restrict__ lat2b, unsigned short* __restrict__ catHL){
    __shared__ __align__(16) unsigned short GH[2][2048];
    __shared__ __align__(16) unsigned short EH[2048];
    __shared__ int sidx[NNB][32];
    const int side = (int)(blockIdx.x >= 1024);
    const unsigned short* lat = side ? latB16 : latA16;
    const int* nb = side ? nb2 : nb1;
    const int t = threadIdx.x;
    const int hb = (blockIdx.x & 1023)*32;
    const int w = t>>6, lane = t&63;
    const int l15 = lane&15, lg = lane>>4;
    const int rowS = t>>3, qS = t&7;
    const int srcOff = (qS ^ (rowS&7))*8;   // swizzle applied at the SOURCE
    for (int e=t; e<NNB*32; e+=256) sidx[e>>5][e&31] = nb[(e>>5)*HL + hb + (e&31)];
    {
        const uint4 z4 = {0,0,0,0};
        *(uint4*)(EH + t*8) = z4;
    }
    __syncthreads();
#define FSTAGE(NN_,BUF_) { \
        const int g_ = sidx[NN_][rowS]; \
        async_cp16(lat + (size_t)g_*72 + srcOff, GH[BUF_] + w*512); }
#define ELOAD(Re_,NN_) { \
        if (t < 32) Re_ = *(const uint2*)(lat + (size_t)sidx[NN_][t]*72 + 64); }
#define EWRITE(Re_,NN_) { \
        if (t < 32){ \
            const int d_ = t*64 + ((((NN_)>>1) ^ (t&7))*8) + (((NN_)&1)*4); \
            *(uint2*)(EH + d_) = Re_; } }
#define SCOMPUTE(NN_,BUF_) { \
        _Pragma("unroll") \
        for (int kt=0; kt<2; ++kt){ \
            s16x8 BH[2]; \
            _Pragma("unroll") \
            for (int ht=0; ht<2; ++ht){ \
                const int h_ = ht*16 + l15; \
                const int qq_ = kt*4 + lg; \
                const int d_ = h_*64 + ((qq_ ^ (h_&7))*8); \
                BH[ht] = *(const s16x8*)(GH[BUF_] + d_); } \
            const int f_ = (NN_)*2 + kt; \
            const s16x8 AH = *(const s16x8*)(SW16 + (f_*4+w)*512 + lane*8); \
            const s16x8 AL = *(const s16x8*)(SW16 + 61440 + (f_*4+w)*512 + lane*8); \
            _Pragma("unroll") \
            for (int ht=0; ht<2; ++ht){ \
                acc[ht] = __builtin_amdgcn_mfma_f32_16x16x32_bf16(AH, BH[ht], acc[ht], 0,0,0); \
                acc[ht] = __builtin_amdgcn_mfma_f32_16x16x32_bf16(AL, BH[ht], acc[ht], 0,0,0); } } }
    uint2 Ae, Be;
    FSTAGE(0,0)
    ELOAD(Ae,0)
    __syncthreads();
    const f32x4 z = {0.f,0.f,0.f,0.f};
    f32x4 acc[2] = {z,z};
    #pragma unroll 1
    for (int nn=0; nn<NNB; ++nn){
        const int cur = nn&1;
        if (nn+1 < NNB) FSTAGE((nn+1),(cur^1))
        EWRITE(Ae,nn)
        if (nn+1 < NNB) ELOAD(Be,(nn+1))
        SCOMPUTE(nn,cur)
        __syncthreads();
        Ae = Be;
    }
#undef FSTAGE
#undef ELOAD
#undef EWRITE
#undef SCOMPUTE
    // el GEMM (K=64 packed across nn, hi-only B)
    #pragma unroll
    for (int kt2=0; kt2<2; ++kt2){
        s16x8 BH[2];
        #pragma unroll
        for (int ht=0; ht<2; ++ht){
            const int h = ht*16 + l15;
            const int qq = kt2*4 + lg;
            const int d = h*64 + ((qq ^ (h&7))*8);
            BH[ht] = *(const s16x8*)(EH + d);
        }
        const s16x8 AH = *(const s16x8*)(SW16 + 122880 + (kt2*4+w)*512 + lane*8);
        const s16x8 AL = *(const s16x8*)(SW16 + 126976 + (kt2*4+w)*512 + lane*8);
        #pragma unroll
        for (int ht=0; ht<2; ++ht){
            acc[ht] = __builtin_amdgcn_mfma_f32_16x16x32_bf16(AH, BH[ht], acc[ht], 0,0,0);
            acc[ht] = __builtin_amdgcn_mfma_f32_16x16x32_bf16(AL, BH[ht], acc[ht], 0,0,0);
        }
    }
    // T = lrelu(acc + sb1) -> hi in GH[0], lo in GH[1]
    {
        const int o0 = w*16 + lg*4;
        float bs1v[4];
        #pragma unroll
        for (int j=0;j<4;++j) bs1v[j] = sb1[o0+j];
        const int q16 = o0>>3;
        #pragma unroll
        for (int ht=0; ht<2; ++ht){
            const int h = ht*16 + l15;
            unsigned short th[4], tl[4];
            #pragma unroll
            for (int j=0;j<4;++j) bf16_hilo(lrelu(acc[ht][j] + bs1v[j]), th[j], tl[j]);
            const int d = h*64 + ((q16 ^ (h&7))*8) + (o0&7);
            *(ushort4*)(GH[0] + d) = make_ushort4(th[0],th[1],th[2],th[3]);
            *(ushort4*)(GH[1] + d) = make_ushort4(tl[0],tl[1],tl[2],tl[3]);
        }
    }
    __syncthreads();
    f32x4 acc2[2] = {z,z};
    #pragma unroll
    for (int kt=0; kt<2; ++kt){
        s16x8 BH[2], BL[2];
        #pragma unroll
        for (int ht=0; ht<2; ++ht){
            const int h = ht*16 + l15;
            const int qq = kt*4 + lg;
            const int d = h*64 + ((qq ^ (h&7))*8);
            BH[ht] = *(const s16x8*)(GH[0] + d);
            BL[ht] = *(const s16x8*)(GH[1] + d);
        }
        const s16x8 AH = *(const s16x8*)(SW16 + 131072 + (kt*4+w)*512 + lane*8);
        const s16x8 AL = *(const s16x8*)(SW16 + 135168 + (kt*4+w)*512 + lane*8);
        #pragma unroll
        for (int ht=0; ht<2; ++ht){
            acc2[ht] = __builtin_amdgcn_mfma_f32_16x16x32_bf16(AH, BH[ht], acc2[ht], 0,0,0);
            acc2[ht] = __builtin_amdgcn_mfma_f32_16x16x32_bf16(AH, BL[ht], acc2[ht], 0,0,0);
            acc2[ht] = __builtin_amdgcn_mfma_f32_16x16x32_bf16(AL, BH[ht], acc2[ht], 0,0,0);
        }
    }
    {
        const int o0 = w*16 + lg*4;
        float bs2v[4];
        #pragma unroll
        for (int j=0;j<4;++j) bs2v[j] = sb2[o0+j];
        #pragma unroll
        for (int ht=0; ht<2; ++ht){
            const int h = hb + ht*16 + l15;
            float v0 = lrelu(acc2[ht][0]+bs2v[0]), v1 = lrelu(acc2[ht][1]+bs2v[1]);
            float v2 = lrelu(acc2[ht][2]+bs2v[2]), v3 = lrelu(acc2[ht][3]+bs2v[3]);
            if (side){
                *(ushort4*)(lat2b + (size_t)h*64 + o0) =
                    make_ushort4(bf16r(v0), bf16r(v1), bf16r(v2), bf16r(v3));
            } else {
                unsigned short th[4], tl[4];
                bf16_hilo(v0, th[0], tl[0]); bf16_hilo(v1, th[1], tl[1]);
                bf16_hilo(v2, th[2], tl[2]); bf16_hilo(v3, th[3], tl[3]);
                *(ushort4*)(catHL + (size_t)h*256 + o0) = make_ushort4(th[0],th[1],th[2],th[3]);
                *(ushort4*)(catHL + (size_t)h*256 + 128 + o0) = make_ushort4(tl[0],tl[1],tl[2],tl[3]);
            }
        }
    }
}

// ---------------------------------------------------------------- corr step (bf16-hi gather, named reg banks, deep prefetch)
__device__ __forceinline__ void corr_step(
        uint4& Gl, uint4& Gh, int& idxq, int knext,
        const unsigned short* __restrict__ lat2b, const int* __restrict__ ci, int hcol, int lg,
        const float* l1f, const float* cb1r, const float* cb2r,
        const s16x8 (&C1H)[2][2], const s16x8 (&C1L)[2][2],
        const s16x8 (&C2H)[2], const s16x8 (&C2L)[2],
        int sel, int srcA, int srcB, float* agg){
    const f32x4 z = {0.f,0.f,0.f,0.f};
    float p[16];
    p[0]=l1f[0]*blo(Gl.x);  p[1]=l1f[1]*bhi(Gl.x);
    p[2]=l1f[2]*blo(Gl.y);  p[3]=l1f[3]*bhi(Gl.y);
    p[4]=l1f[4]*blo(Gl.z);  p[5]=l1f[5]*bhi(Gl.z);
    p[6]=l1f[6]*blo(Gl.w);  p[7]=l1f[7]*bhi(Gl.w);
    p[8]=l1f[8]*blo(Gh.x);  p[9]=l1f[9]*bhi(Gh.x);
    p[10]=l1f[10]*blo(Gh.y); p[11]=l1f[11]*bhi(Gh.y);
    p[12]=l1f[12]*blo(Gh.z); p[13]=l1f[13]*bhi(Gh.z);
    p[14]=l1f[14]*blo(Gh.w); p[15]=l1f[15]*bhi(Gh.w);
    {
        const unsigned short* r = lat2b + (size_t)idxq*64 + lg*8;
        Gl = *(const uint4*)r;
        Gh = *(const uint4*)(r + 32);
    }
    idxq = ci[knext*HL + hcol];
    pk8 BH[2], BL[2];
    #pragma unroll
    for (int kt=0; kt<2; ++kt)
        #pragma unroll
        for (int q=0; q<4; ++q)
            fsplit2(p[kt*8+2*q], p[kt*8+2*q+1], BH[kt].u[q], BL[kt].u[q]);
    f32x4 a1[2] = {z, z};
    #pragma unroll
    for (int kt=0; kt<2; ++kt){
        a1[0] = __builtin_amdgcn_mfma_f32_16x16x32_bf16(C1H[0][kt], BH[kt].v, a1[0], 0,0,0);
        a1[1] = __builtin_amdgcn_mfma_f32_16x16x32_bf16(C1H[1][kt], BH[kt].v, a1[1], 0,0,0);
        a1[0] = __builtin_amdgcn_mfma_f32_16x16x32_bf16(C1H[0][kt], BL[kt].v, a1[0], 0,0,0);
        a1[1] = __builtin_amdgcn_mfma_f32_16x16x32_bf16(C1H[1][kt], BL[kt].v, a1[1], 0,0,0);
        a1[0] = __builtin_amdgcn_mfma_f32_16x16x32_bf16(C1L[0][kt], BH[kt].v, a1[0], 0,0,0);
        a1[1] = __builtin_amdgcn_mfma_f32_16x16x32_bf16(C1L[1][kt], BH[kt].v, a1[1], 0,0,0);
    }
    unsigned mh[2][2], ml[2][2];
    #pragma unroll
    for (int ot=0; ot<2; ++ot)
        #pragma unroll
        for (int j=0; j<2; ++j)
            fsplit2(lrelu(a1[ot][2*j]   + cb1r[ot*4+2*j]),
                    lrelu(a1[ot][2*j+1] + cb1r[ot*4+2*j+1]), mh[ot][j], ml[ot][j]);
    pk8 B2H = shuf32(mh[0], mh[1], sel, srcA, srcB);
    pk8 B2L = shuf32(ml[0], ml[1], sel, srcA, srcB);
    f32x4 a2[2] = {z, z};
    a2[0] = __builtin_amdgcn_mfma_f32_16x16x32_bf16(C2H[0], B2H.v, a2[0], 0,0,0);
    a2[1] = __builtin_amdgcn_mfma_f32_16x16x32_bf16(C2H[1], B2H.v, a2[1], 0,0,0);
    a2[0] = __builtin_amdgcn_mfma_f32_16x16x32_bf16(C2H[0], B2L.v, a2[0], 0,0,0);
    a2[1] = __builtin_amdgcn_mfma_f32_16x16x32_bf16(C2H[1], B2L.v, a2[1], 0,0,0);
    a2[0] = __builtin_amdgcn_mfma_f32_16x16x32_bf16(C2L[0], B2H.v, a2[0], 0,0,0);
    a2[1] = __builtin_amdgcn_mfma_f32_16x16x32_bf16(C2L[1], B2H.v, a2[1], 0,0,0);
    #pragma unroll
    for (int i=0;i<8;++i)
        agg[i] += lrelu(a2[i>>2][i&3] + cb2r[i]);
}

// ---------------------------------------------------------------- corr + d-MLP, 4-way split-K (natural VGPR, grid-fed occupancy)
__global__ __launch_bounds__(256, 4) void corr_mfma_kernel(
        const unsigned short* __restrict__ lat2b, const int* __restrict__ ci,
        const unsigned short* __restrict__ W16,
        const float* __restrict__ cb1, const float* __restrict__ cb2,
        const float* __restrict__ db1, const float* __restrict__ db2,
        unsigned short* __restrict__ catHL){
    __shared__ float AGG[3][64][8];
    const int t = threadIdx.x;
    const int lane = t & 63;
    const int l15 = lane & 15, lg = lane >> 4;
    const int w = t >> 6;                 // 0..3 = K-quarter
    const int hcol = blockIdx.x*16 + l15; // 2048 blocks x 16 cols
    const int srcA = (l15 + ((lg&1)*32)) * 4;
    const int srcB = srcA + 64;
    const int sel = (lg>>1) & 1;

    s16x8 C1H[2][2], C1L[2][2], C2H[2], C2L[2];
    #pragma unroll
    for (int ot=0; ot<2; ++ot){
        #pragma unroll
        for (int kt=0; kt<2; ++kt){
            C1H[ot][kt] = *(const s16x8*)(W16 + (ot*2+kt)*512 + lane*8);
            C1L[ot][kt] = *(const s16x8*)(W16 + 2048 + (ot*2+kt)*512 + lane*8);
        }
        C2H[ot] = *(const s16x8*)(W16 + 4096 + ot*512 + lane*8);
        C2L[ot] = *(const s16x8*)(W16 + 5120 + ot*512 + lane*8);
    }
    float l1f[16];
    {
        const unsigned short* hr = catHL + (size_t)hcol*256;
        const unsigned short* lr = hr + 128;
        const ushort4 h0 = *(const ushort4*)(hr + lg*8);
        const ushort4 h1 = *(const ushort4*)(hr + lg*8 + 4);
        const ushort4 h2 = *(const ushort4*)(hr + 32 + lg*8);
        const ushort4 h3 = *(const ushort4*)(hr + 32 + lg*8 + 4);
        const ushort4 l0 = *(const ushort4*)(lr + lg*8);
        const ushort4 l1 = *(const ushort4*)(lr + lg*8 + 4);
        const ushort4 l2 = *(const ushort4*)(lr + 32 + lg*8);
        const ushort4 l3 = *(const ushort4*)(lr + 32 + lg*8 + 4);
        l1f[0]=bf2f(h0.x,l0.x); l1f[1]=bf2f(h0.y,l0.y); l1f[2]=bf2f(h0.z,l0.z); l1f[3]=bf2f(h0.w,l0.w);
        l1f[4]=bf2f(h1.x,l1.x); l1f[5]=bf2f(h1.y,l1.y); l1f[6]=bf2f(h1.z,l1.z); l1f[7]=bf2f(h1.w,l1.w);
        l1f[8]=bf2f(h2.x,l2.x); l1f[9]=bf2f(h2.y,l2.y); l1f[10]=bf2f(h2.z,l2.z); l1f[11]=bf2f(h2.w,l2.w);
        l1f[12]=bf2f(h3.x,l3.x); l1f[13]=bf2f(h3.y,l3.y); l1f[14]=bf2f(h3.z,l3.z); l1f[15]=bf2f(h3.w,l3.w);
    }
    float cb1r[8], cb2r[8];
    #pragma unroll
    for (int i=0;i<8;++i){
        cb1r[i] = cb1[(i>>2)*16 + lg*4 + (i&3)];
        cb2r[i] = cb2[(i>>2)*16 + lg*4 + (i&3)];
    }
    float agg[8] = {};
    const f32x4 z = {0.f,0.f,0.f,0.f};

    const int kbeg = w*8;
    int idx0 = ci[(kbeg+0)*HL + hcol];
    int idx1 = ci[(kbeg+1)*HL + hcol];
    uint4 GaL,GaH, GbL,GbH;
    {
        const unsigned short* r = lat2b + (size_t)idx0*64 + lg*8;
        GaL = *(const uint4*)r;  GaH = *(const uint4*)(r + 32);
    }
    {
        const unsigned short* r = lat2b + (size_t)idx1*64 + lg*8;
        GbL = *(const uint4*)r;  GbH = *(const uint4*)(r + 32);
    }
    idx0 = ci[(kbeg+2)*HL + hcol];
    idx1 = ci[(kbeg+3)*HL + hcol];
    #pragma unroll 1
    for (int k2=0; k2<4; ++k2){
        const int ke = kbeg + 2*k2;
        corr_step(GaL,GaH, idx0, min(ke+4, 31), lat2b, ci, hcol, lg,
                  l1f, cb1r, cb2r, C1H, C1L, C2H, C2L, sel, srcA, srcB, agg);
        corr_step(GbL,GbH, idx1, min(ke+5, 31), lat2b, ci, hcol, lg,
                  l1f, cb1r, cb2r, C1H, C1L, C2H, C2L, sel, srcA, srcB, agg);
    }
    if (w){
        #pragma unroll
        for (int i=0;i<8;++i) AGG[w-1][lane][i] = agg[i];
    }
    __syncthreads();
    if (w) return;
    #pragma unroll
    for (int i=0;i<8;++i)
        agg[i] = (agg[i] + AGG[0][lane][i] + AGG[1][lane][i] + AGG[2][lane][i]) * (1.0f/32.0f);
    unsigned agH[2][2], agL[2][2];
    #pragma unroll
    for (int ot=0; ot<2; ++ot)
        #pragma unroll
        for (int j=0; j<2; ++j)
            fsplit2(agg[ot*4+2*j], agg[ot*4+2*j+1], agH[ot][j], agL[ot][j]);
    pk8 B3H = shuf32(agH[0], agH[1], sel, srcA, srcB);
    pk8 B3L = shuf32(agL[0], agL[1], sel, srcA, srcB);
    float db1r[16], db2r[16];
    #pragma unroll
    for (int i=0;i<16;++i){
        db1r[i] = db1[(i>>2)*16 + lg*4 + (i&3)];
        db2r[i] = db2[(i>>2)*16 + lg*4 + (i&3)];
    }
    unsigned d1H[4][2], d1L[4][2];
    #pragma unroll
    for (int ot=0; ot<4; ++ot){
        s16x8 AH = *(const s16x8*)(W16 + 6144 + ot*512 + lane*8);
        s16x8 AL = *(const s16x8*)(W16 + 8192 + ot*512 + lane*8);
        f32x4 a3 = z;
        a3 = __builtin_amdgcn_mfma_f32_16x16x32_bf16(AH, B3H.v, a3, 0,0,0);
        a3 = __builtin_amdgcn_mfma_f32_16x16x32_bf16(AH, B3L.v, a3, 0,0,0);
        a3 = __builtin_amdgcn_mfma_f32_16x16x32_bf16(AL, B3H.v, a3, 0,0,0);
        #pragma unroll
        for (int j=0;j<2;++j)
            fsplit2(lrelu(a3[2*j]   + db1r[ot*4+2*j]),
                    lrelu(a3[2*j+1] + db1r[ot*4+2*j+1]), d1H[ot][j], d1L[ot][j]);
    }
    f32x4 a4[4] = {z,z,z,z};
    #pragma unroll
    for (int kt=0; kt<2; ++kt){
        pk8 B4H = shuf32(d1H[kt*2], d1H[kt*2+1], sel, srcA, srcB);
        pk8 B4L = shuf32(d1L[kt*2], d1L[kt*2+1], sel, srcA, srcB);
        #pragma unroll
        for (int ot=0; ot<4; ++ot){
            s16x8 AH = *(const s16x8*)(W16 + 10240 + (ot*2+kt)*512 + lane*8);
            s16x8 AL = *(const s16x8*)(W16 + 14336 + (ot*2+kt)*512 + lane*8);
            a4[ot] = __builtin_amdgcn_mfma_f32_16x16x32_bf16(AH, B4H.v, a4[ot], 0,0,0);
            a4[ot] = __builtin_amdgcn_mfma_f32_16x16x32_bf16(AH, B4L.v, a4[ot], 0,0,0);
            a4[ot] = __builtin_amdgcn_mfma_f32_16x16x32_bf16(AL, B4H.v, a4[ot], 0,0,0);
        }
    }
    unsigned short* dH = catHL + (size_t)hcol*256 + 64;
    unsigned short* dL = catHL + (size_t)hcol*256 + 192;
    #pragma unroll
    for (int ot=0; ot<4; ++ot){
        float v0 = lrelu(a4[ot][0]+db2r[ot*4+0]), v1 = lrelu(a4[ot][1]+db2r[ot*4+1]);
        float v2 = lrelu(a4[ot][2]+db2r[ot*4+2]), v3 = lrelu(a4[ot][3]+db2r[ot*4+3]);
        unsigned short th[4], tl[4];
        fsplit1(v0, th[0], tl[0]); fsplit1(v1, th[1], tl[1]);
        fsplit1(v2, th[2], tl[2]); fsplit1(v3, th[3], tl[3]);
        *(ushort4*)(dH + ot*16 + lg*4) = make_ushort4(th[0],th[1],th[2],th[3]);
        *(ushort4*)(dL + ot*16 + lg*4) = make_ushort4(tl[0],tl[1],tl[2],tl[3]);
    }
}

// ---------------------------------------------------------------- blur_p: async global_load_lds staging (swizzled source, linear LDS)
__global__ __launch_bounds__(512) void blur_p_mfma_kernel(
        const unsigned short* __restrict__ catHL,
        const int* __restrict__ nb,
        const unsigned short* __restrict__ pw1fH, const unsigned short* __restrict__ pw1fL,
        const float* __restrict__ pb1,
        const unsigned short* __restrict__ pw2fH, const unsigned short* __restrict__ pw2fL,
        const float* __restrict__ pb2,
        unsigned short* __restrict__ p16){
    __shared__ __align__(16) unsigned short GH[2][4096];
    __shared__ int sidx[NNB][32];
    const int t = threadIdx.x;
    const int hb = blockIdx.x*32;
    const int w = t>>6, lane = t&63;
    const int l15 = lane&15, lg = lane>>4;
    const int row = t>>4, q = t&15;
    const int srcOff = (q ^ (row&7))*8;       // swizzle applied at the SOURCE
    for (int e=t; e<NNB*32; e+=512) sidx[e>>5][e&31] = nb[(e>>5)*HL + hb + (e&31)];
    const f32x4 z = {0.f,0.f,0.f,0.f};
    f32x4 acc1[2] = {z,z};
    __syncthreads();
#define PSTAGE(NN_,BUF_) { \
        const int g_ = sidx[NN_][row]; \
        async_cp16(catHL + (size_t)g_*256 + srcOff, GH[BUF_] + w*512); }
#define PCOMPUTE(NN_,BUF_) { \
        _Pragma("unroll") \
        for (int kt=0; kt<4; ++kt){ \
            s16x8 BH[2]; \
            _Pragma("unroll") \
            for (int ht=0; ht<2; ++ht){ \
                const int h_ = ht*16 + l15; \
                const int qq_ = kt*4 + lg; \
                const int d_ = h_*128 + ((qq_ ^ (h_&7))*8); \
                BH[ht] = *(const s16x8*)(GH[BUF_] + d_); } \
            const size_t fo_ = ((size_t)(((NN_)*4 + kt)*8 + w))*512 + lane*8; \
            const s16x8 AH = *(const s16x8*)(pw1fH + fo_); \
            const s16x8 AL = *(const s16x8*)(pw1fL + fo_); \
            _Pragma("unroll") \
            for (int ht=0; ht<2; ++ht){ \
                acc1[ht] = __builtin_amdgcn_mfma_f32_16x16x32_bf16(AH, BH[ht], acc1[ht], 0,0,0); \
                acc1[ht] = __builtin_amdgcn_mfma_f32_16x16x32_bf16(AL, BH[ht], acc1[ht], 0,0,0); } } }
    PSTAGE(0,0)
    __syncthreads();
    #pragma unroll 1
    for (int nn=0; nn<NNB; ++nn){
        const int cur = nn&1;
        if (nn+1 < NNB) PSTAGE((nn+1),(cur^1))
        PCOMPUTE(nn,cur)
        __syncthreads();
    }
#undef PSTAGE
#undef PCOMPUTE
    // epilogue 1: T = lrelu(acc1 + pb1); hi -> GH[0], lo -> GH[1]
    {
        const int o0 = w*16 + lg*4;
        const float b0 = pb1[o0], b1v = pb1[o0+1], b2v = pb1[o0+2], b3v = pb1[o0+3];
        const int qc = o0>>3;
        #pragma unroll
        for (int ht=0; ht<2; ++ht){
            const int h = ht*16 + l15;
            unsigned short th[4], tl[4];
            bf16_hilo(lrelu(acc1[ht][0] + b0), th[0], tl[0]);
            bf16_hilo(lrelu(acc1[ht][1] + b1v), th[1], tl[1]);
            bf16_hilo(lrelu(acc1[ht][2] + b2v), th[2], tl[2]);
            bf16_hilo(lrelu(acc1[ht][3] + b3v), th[3], tl[3]);
            const int d = h*128 + ((qc ^ (h&7))*8) + (o0&7);
            *(ushort4*)(GH[0] + d) = make_ushort4(th[0],th[1],th[2],th[3]);
            *(ushort4*)(GH[1] + d) = make_ushort4(tl[0],tl[1],tl[2],tl[3]);
        }
    }
    __syncthreads();
    f32x4 acc2[2] = {z,z};
    #pragma unroll
    for (int kt=0; kt<4; ++kt){
        s16x8 BH[2], BL[2];
        #pragma unroll
        for (int ht=0; ht<2; ++ht){
            const int h = ht*16 + l15;
            const int qq = kt*4 + lg;
            const int d = h*128 + ((qq ^ (h&7))*8);
            BH[ht] = *(const s16x8*)(GH[0] + d);
            BL[ht] = *(const s16x8*)(GH[1] + d);
        }
        const size_t fo = ((size_t)(kt*8 + w))*512 + lane*8;
        const s16x8 AH = *(const s16x8*)(pw2fH + fo);
        const s16x8 AL = *(const s16x8*)(pw2fL + fo);
        #pragma unroll
        for (int ht=0; ht<2; ++ht){
            acc2[ht] = __builtin_amdgcn_mfma_f32_16x16x32_bf16(AH, BH[ht], acc2[ht], 0,0,0);
            acc2[ht] = __builtin_amdgcn_mfma_f32_16x16x32_bf16(AH, BL[ht], acc2[ht], 0,0,0);
            acc2[ht] = __builtin_amdgcn_mfma_f32_16x16x32_bf16(AL, BH[ht], acc2[ht], 0,0,0);
        }
    }
    {
        const int o0 = w*16 + lg*4;
        const float b0 = pb2[o0], b1v = pb2[o0+1], b2v = pb2[o0+2], b3v = pb2[o0+3];
        #pragma unroll
        for (int ht=0; ht<2; ++ht){
            const int h = hb + ht*16 + l15;
            *(ushort4*)(p16 + (size_t)h*128 + o0) = make_ushort4(
                bf16r(lrelu(acc2[ht][0] + b0)),  bf16r(lrelu(acc2[ht][1] + b1v)),
                bf16r(lrelu(acc2[ht][2] + b2v)), bf16r(lrelu(acc2[ht][3] + b3v)));
        }
    }
}

// ---------------------------------------------------------------- head: slice (bf16 p) + 128->128->64->3
__global__ __launch_bounds__(256) void head_kernel(
        const unsigned short* __restrict__ p16, const float* __restrict__ bary, const int* __restrict__ off,
        const float* __restrict__ fw2T, const float* __restrict__ fb2,
        const float* __restrict__ fw3T, const float* __restrict__ fb3,
        const float* __restrict__ fw4, const float* __restrict__ fb4,
        float* __restrict__ out){
    __shared__ __align__(16) float S[8704];
    __shared__ __align__(16) float WW[8192];
    __shared__ float SB[5][64];
    __shared__ int   SO[5][64];
    const int t = threadIdx.x;
    const int pb = blockIdx.x*64;
    const int oq8 = t>>4, pq = t&15;
    if (t<64){
        #pragma unroll
        for (int j=0;j<5;++j){ SB[j][t]=bary[j*NPTS+pb+t]; SO[j][t]=off[j*NPTS+pb+t]; }
    }
    __syncthreads();
    // stage S[c][pt]: 16 threads/row x 8 ch, 4 row-passes
    {
        const int qh = t & 15, rg = t >> 4;
        #pragma unroll
        for (int i=0;i<4;++i){
            const int row = rg + 16*i;
            float sa[8] = {0.f,0.f,0.f,0.f,0.f,0.f,0.f,0.f};
            #pragma unroll
            for (int j=0;j<5;++j){
                const uint4 v = *(const uint4*)(p16 + (size_t)SO[j][row]*128 + qh*8);
                const float b = SB[j][row];
                sa[0]+=b*blo(v.x); sa[1]+=b*bhi(v.x);
                sa[2]+=b*blo(v.y); sa[3]+=b*bhi(v.y);
                sa[4]+=b*blo(v.z); sa[5]+=b*bhi(v.z);
                sa[6]+=b*blo(v.w); sa[7]+=b*bhi(v.w);
            }
            #pragma unroll
            for (int c=0;c<8;++c) S[(qh*8+c)*68 + row] = sa[c];
        }
    }
    float acc1[8][4] = {};
    #pragma unroll 1
    for (int hf=0;hf<2;++hf){
        if (hf==1) __syncthreads();
        for (int e=t;e<2048;e+=256)
            *(float4*)(WW + e*4) = *(const float4*)(fw2T + hf*8192 + e*4);
        __syncthreads();
        #pragma unroll 4
        for (int c=0;c<64;++c){
            const float4 a4 = *(const float4*)(S + (hf*64+c)*68 + pq*4);
            const float4 wa = *(const float4*)(WW + c*128 + oq8*8);
            const float4 wb = *(const float4*)(WW + c*128 + oq8*8 + 4);
            const float av[4]={a4.x,a4.y,a4.z,a4.w};
            const float wv[8]={wa.x,wa.y,wa.z,wa.w,wb.x,wb.y,wb.z,wb.w};
            #pragma unroll
            for (int i=0;i<8;++i)
                #pragma unroll
                for (int j=0;j<4;++j)
                    acc1[i][j] = fmaf(wv[i], av[j], acc1[i][j]);
        }
    }
    __syncthreads();
    float bf2v[8];
    #pragma unroll
    for (int i=0;i<8;++i) bf2v[i]=fb2[oq8*8+i];
    #pragma unroll
    for (int i=0;i<8;++i){
        const int o = oq8*8+i;
        float4 v = make_float4(lrelu(acc1[i][0]+bf2v[i]), lrelu(acc1[i][1]+bf2v[i]),
                               lrelu(acc1[i][2]+bf2v[i]), lrelu(acc1[i][3]+bf2v[i]));
        *(float4*)(S + o*68 + pq*4) = v;
    }
    for (int e=t;e<2048;e+=256)
        *(float4*)(WW + e*4) = *(const float4*)(fw3T + e*4);
    __syncthreads();
    const int od = t>>4;
    float bf3[4];
    #pragma unroll
    for (int i=0;i<4;++i) bf3[i]=fb3[od*4+i];
    float a2[4][4] = {};
    #pragma unroll 4
    for (int c=0;c<128;++c){
        const float4 a4 = *(const float4*)(S + c*68 + pq*4);
        const float4 w4 = *(const float4*)(WW + c*64 + od*4);
        const float av[4]={a4.x,a4.y,a4.z,a4.w};
        const float wv[4]={w4.x,w4.y,w4.z,w4.w};
        #pragma unroll
        for (int i=0;i<4;++i)
            #pragma unroll
            for (int j=0;j<4;++j)
                a2[i][j] = fmaf(wv[i], av[j], a2[i][j]);
    }
    __syncthreads();
    #pragma unroll
    for (int i=0;i<4;++i){
        float4 v = make_float4(lrelu(a2[i][0]+bf3[i]), lrelu(a2[i][1]+bf3[i]),
                               lrelu(a2[i][2]+bf3[i]), lrelu(a2[i][3]+bf3[i]));
        *(float4*)(S + (od*4+i)*68 + pq*4) = v;
    }
    __syncthreads();
    if (t < 192){
        const int r = t>>6, pp = t&63;
        float a = fb4[r];
        #pragma unroll 8
        for (int c=0;c<64;++c) a += fw4[r*64+c]*S[c*68+pp];
        out[r*NPTS + pb + pp] = a;
    }
}

// ================================================================ launch
extern "C" void kernel_launch(void* const* d_in, const int* in_sizes, int n_in,
                              void* d_out, int out_size, void* d_ws, size_t ws_size,
                              hipStream_t stream){
    const float* pc1   = (const float*)d_in[0];
    const float* pc2   = (const float*)d_in[1];
    const float* el1   = (const float*)d_in[2];
    const float* el2   = (const float*)d_in[3];
    const float* bary1 = (const float*)d_in[4];
    const float* bary2 = (const float*)d_in[5];
    const int*   off1  = (const int*)d_in[6];
    const int*   off2  = (const int*)d_in[7];
    const int*   nb1   = (const int*)d_in[8];
    const int*   nb2   = (const int*)d_in[9];
    const int*   ci    = (const int*)d_in[10];
    const float* w1    = (const float*)d_in[11];
    const float* b1    = (const float*)d_in[12];
    const float* w2    = (const float*)d_in[13];
    const float* b2    = (const float*)d_in[14];
    const float* w3    = (const float*)d_in[15];
    const float* b3    = (const float*)d_in[16];
    const float* sw1   = (const float*)d_in[17];
    const float* sb1   = (const float*)d_in[18];
    const float* sw2   = (const float*)d_in[19];
    const float* sb2   = (const float*)d_in[20];
    const float* cw1   = (const float*)d_in[21];
    const float* cb1   = (const float*)d_in[22];
    const float* cw2   = (const float*)d_in[23];
    const float* cb2   = (const float*)d_in[24];
    const float* dw1   = (const float*)d_in[25];
    const float* db1   = (const float*)d_in[26];
    const float* dw2   = (const float*)d_in[27];
    const float* db2   = (const float*)d_in[28];
    const float* pw1   = (const float*)d_in[29];
    const float* pb1   = (const float*)d_in[30];
    const float* pw2   = (const float*)d_in[31];
    const float* pb2   = (const float*)d_in[32];
    const float* fw2   = (const float*)d_in[33];
    const float* fb2   = (const float*)d_in[34];
    const float* fw3   = (const float*)d_in[35];
    const float* fb3   = (const float*)d_in[36];
    const float* fw4   = (const float*)d_in[37];
    const float* fb4   = (const float*)d_in[38];
    float* out = (float*)d_out;

    float* ws    = (float*)d_ws;
    float* pf1f  = ws;                    // 2228224 floats region ; pfeat bf16 + later p16
    float* pf2f  = pf1f  + 2228224;
    float* bkt   = pf2f  + 2228224;       // 4456448 (buckets) ; later catHL
    float* lat16 = bkt   + 4456448;       // compact hi lattice: 2*HL*72 ushorts
    float* lat2f = lat16 + 4456448;       // lat2b bf16 (HL*64 ushorts)
    float* pw1fS = lat2f + 2097152;       // 245760
    float* SW16f = pw1fS + 245760;        // 69632
    float* W16f  = SW16f + 69632;         // 9216
    float* pw2fS = W16f  + 9216;          // 16384
    float* fw2T  = pw2fS + 16384;         // 16384
    float* fw3T  = fw2T  + 16384;         // 8192
    float* cntf  = fw3T  + 8192;          // 16384 ints

    unsigned short* pw1fH = (unsigned short*)pw1fS;
    unsigned short* pw1fL = pw1fH + 245760;
    unsigned short* SW16  = (unsigned short*)SW16f;
    unsigned short* W16   = (unsigned short*)W16f;
    unsigned short* pw2fH = (unsigned short*)pw2fS;
    unsigned short* pw2fL = pw2fH + 16384;
    int*   cnt  = (int*)cntf;
    int*   bnA  = (int*)bkt;
    float* bvA  = bkt + (size_t)HL*BCAP;
    int*   bnB  = (int*)(bkt + 2228224);
    float* bvB  = bkt + 2228224 + (size_t)HL*BCAP;
    unsigned short* pf1 = (unsigned short*)pf1f;         // NPTS*72 bf16
    unsigned short* pf2 = (unsigned short*)pf2f;
    unsigned short* latA16 = (unsigned short*)lat16;     // HL*72 compact hi
    unsigned short* latB16 = latA16 + (size_t)HL*72;
    unsigned short* catHL  = (unsigned short*)bkt;       // HL*256 (buckets dead)
    unsigned short* lat2b  = (unsigned short*)lat2f;     // HL*64 bf16-hi
    unsigned short* p16    = (unsigned short*)pf1f;      // HL*128 bf16 (pfeat dead)

    init_kernel<<<960, 256, 0, stream>>>(cnt,
                                         sw1, pw1, sw2, cw1, cw2, dw1, dw2, pw2, fw2, fw3,
                                         SW16, pw1fH, pw1fL, W16,
                                         pw2fH, pw2fL, fw2T, fw3T);

    mlp3_kernel<<<256, 256, 0, stream>>>(pc1, el1, pc2, el2, w1,b1,w2,b2,w3,b3, pf1, pf2);

    bucket_kernel<<<1280, 256, 0, stream>>>(bary1, bary2, off1, off2, cnt,
                                            bnA, bvA, bnB, bvB);

    splat2_kernel<<<16384, 256, 0, stream>>>(pf1, pf2, cnt, bnA, bvA, bnB, bvB,
                                             latA16, latB16);

    blur_s_mfma_kernel<<<2048, 256, 0, stream>>>(latA16, latB16, nb1, nb2, SW16, sb1, sb2,
                                                 lat2b, catHL);

    corr_mfma_kernel<<<2048, 256, 0, stream>>>(lat2b, ci, W16, cb1, cb2, db1, db2, catHL);

    blur_p_mfma_kernel<<<1024, 512, 0, stream>>>(catHL, nb1, pw1fH, pw1fL, pb1,
                                                 pw2fH, pw2fL, pb2, p16);

    head_kernel<<<512, 256, 0, stream>>>(p16, bary1, off1, fw2T,fb2,fw3T,fb3,fw4,fb4, out);
}

// Round 24
// 256.380 us; speedup vs baseline: 1.4339x; 1.0220x over previous
//
#include <hip/hip_runtime.h>

#define NPTS 32768
#define HL   32768
#define NNB  15
#define KC   32
#define BCAP 32

typedef __attribute__((ext_vector_type(8))) short s16x8;
typedef __attribute__((ext_vector_type(4))) float f32x4;

typedef union { s16x8 v; unsigned u[4]; } pk8;

__device__ __forceinline__ float lrelu(float x){ return x > 0.0f ? x : 0.1f*x; }

__device__ __forceinline__ unsigned short bf16r(float x){
    union { float f; unsigned u; } a; a.f = x;
    unsigned r = a.u + 0x7FFF + ((a.u >> 16) & 1);
    return (unsigned short)(r >> 16);
}
__device__ __forceinline__ unsigned pk2(unsigned short a, unsigned short b){
    return (unsigned)a | ((unsigned)b << 16);
}
__device__ __forceinline__ void bf16_hilo(float x, unsigned short& hi, unsigned short& lo){
    hi = bf16r(x);
    union { float f; unsigned u; } b; b.u = ((unsigned)hi) << 16;
    lo = bf16r(x - b.f);
}
__device__ __forceinline__ void fsplit2(float a, float b, unsigned &h, unsigned &l){
    unsigned ua = __float_as_uint(a), ub = __float_as_uint(b);
    unsigned ha = ua & 0xFFFF0000u, hb = ub & 0xFFFF0000u;
    float ra = a - __uint_as_float(ha);
    float rb = b - __uint_as_float(hb);
    h = (ha >> 16) | hb;
    l = (__float_as_uint(ra) >> 16) | (__float_as_uint(rb) & 0xFFFF0000u);
}
__device__ __forceinline__ void fsplit1(float a, unsigned short &h, unsigned short &l){
    unsigned ua = __float_as_uint(a);
    unsigned ha = ua & 0xFFFF0000u;
    float ra = a - __uint_as_float(ha);
    h = (unsigned short)(ua >> 16);
    l = (unsigned short)(__float_as_uint(ra) >> 16);
}
__device__ __forceinline__ float bf2f(unsigned short h, unsigned short l){
    return __uint_as_float(((unsigned)h)<<16) + __uint_as_float(((unsigned)l)<<16);
}
__device__ __forceinline__ float blo(unsigned u){ return __uint_as_float(u << 16); }
__device__ __forceinline__ float bhi(unsigned u){ return __uint_as_float(u & 0xFFFF0000u); }
__device__ __forceinline__ float us2f(unsigned short u){ return __uint_as_float(((unsigned)u)<<16); }

__device__ __forceinline__ void async_cp16(const unsigned short* g, unsigned short* l){
    __builtin_amdgcn_global_load_lds(
        (const __attribute__((address_space(1))) unsigned int*)g,
        (__attribute__((address_space(3))) unsigned int*)l,
        16, 0, 0);
}

__device__ __forceinline__ pk8 shuf32(const unsigned* p0, const unsigned* p1,
                                      int sel, int srcA, int srcB){
    pk8 o;
    int a0 = __builtin_amdgcn_ds_bpermute(srcA, (int)p0[0]);
    int a1 = __builtin_amdgcn_ds_bpermute(srcA, (int)p1[0]);
    o.u[0] = (unsigned)(sel ? a1 : a0);
    int b0 = __builtin_amdgcn_ds_bpermute(srcA, (int)p0[1]);
    int b1 = __builtin_amdgcn_ds_bpermute(srcA, (int)p1[1]);
    o.u[1] = (unsigned)(sel ? b1 : b0);
    int c0 = __builtin_amdgcn_ds_bpermute(srcB, (int)p0[0]);
    int c1 = __builtin_amdgcn_ds_bpermute(srcB, (int)p1[0]);
    o.u[2] = (unsigned)(sel ? c1 : c0);
    int d0 = __builtin_amdgcn_ds_bpermute(srcB, (int)p0[1]);
    int d1 = __builtin_amdgcn_ds_bpermute(srcB, (int)p1[1]);
    o.u[3] = (unsigned)(sel ? d1 : d0);
    return o;
}

// ---------------------------------------------------------------- init: zero counters + repack weights
__global__ void init_kernel(int* __restrict__ cnt,
                              const float* __restrict__ sw1, const float* __restrict__ pw1,
                              const float* __restrict__ sw2, const float* __restrict__ cw1,
                              const float* __restrict__ cw2, const float* __restrict__ dw1,
                              const float* __restrict__ dw2, const float* __restrict__ pw2,
                              const float* __restrict__ fw2, const float* __restrict__ fw3,
                              unsigned short* __restrict__ SW16,
                              unsigned short* __restrict__ pw1fH, unsigned short* __restrict__ pw1fL,
                              unsigned short* __restrict__ W16,
                              unsigned short* __restrict__ pw2fH, unsigned short* __restrict__ pw2fL,
                              float* __restrict__ fw2T, float* __restrict__ fw3T){
    int tid = blockIdx.x*256 + threadIdx.x;
    if (tid < 2*HL) cnt[tid] = 0;
    if (tid < 61440){
        int b = tid&7, ln = (tid>>3)&63, ot = (tid>>9)&3, f = tid>>11;
        int kt = f&1, nn = f>>1;
        int o = ot*16 + (ln&15), k = kt*32 + (ln>>4)*8 + b, c = k + 4;
        unsigned short hi, lo; bf16_hilo(sw1[(o*68+c)*15+nn], hi, lo);
        SW16[tid] = hi; SW16[61440+tid] = lo;
    }
    if (tid < 4096){
        int b = tid&7, ln = (tid>>3)&63, ot = (tid>>9)&3, kt2 = tid>>11;
        int o = ot*16 + (ln&15), k2 = kt2*32 + (ln>>4)*8 + b;
        float v = (k2 < 60) ? sw1[(o*68 + (k2&3))*15 + (k2>>2)] : 0.f;
        unsigned short hi, lo; bf16_hilo(v, hi, lo);
        SW16[122880+tid] = hi; SW16[126976+tid] = lo;
    }
    if (tid < 4096){
        int b = tid&7, ln = (tid>>3)&63, ot = (tid>>9)&3, kt = tid>>11;
        int o = ot*16 + (ln&15), k = kt*32 + (ln>>4)*8 + b;
        unsigned short hi, lo; bf16_hilo(sw2[o*64+k], hi, lo);
        SW16[131072+tid] = hi; SW16[135168+tid] = lo;
    }
    if (tid < 245760){
        int b = tid & 7, ln = (tid>>3)&63, ot = (tid>>9)&7, kt = (tid>>12)&3, nn = tid>>14;
        int o = ot*16 + (ln&15), k = kt*32 + (ln>>4)*8 + b;
        float v = pw1[(o*128 + k)*15 + nn];
        unsigned short hi, lo; bf16_hilo(v, hi, lo);
        pw1fH[tid] = hi; pw1fL[tid] = lo;
    }
    if (tid < 16384){
        int b = tid & 7, ln = (tid>>3)&63, ot = (tid>>9)&7, kt = (tid>>12)&3;
        int o = ot*16 + (ln&15), k = kt*32 + (ln>>4)*8 + b;
        float v = pw2[o*128 + k];
        unsigned short hi, lo; bf16_hilo(v, hi, lo);
        pw2fH[tid] = hi; pw2fL[tid] = lo;
    }
    if (tid < 2048){
        int b = tid&7, ln = (tid>>3)&63, f = tid>>9;
        int ot = f>>1, kt = f&1;
        int o = ot*16 + (ln&15), c = kt*32 + (ln>>4)*8 + b;
        unsigned short hi, lo; bf16_hilo(cw1[o*64+c], hi, lo);
        W16[tid] = hi; W16[2048+tid] = lo;
    }
    if (tid < 1024){
        int b = tid&7, ln = (tid>>3)&63, ot = tid>>9;
        int o = ot*16 + (ln&15), c = (ln>>4)*8 + b;
        unsigned short hi, lo; bf16_hilo(cw2[o*32+c], hi, lo);
        W16[4096+tid] = hi; W16[5120+tid] = lo;
    }
    if (tid < 2048){
        int b = tid&7, ln = (tid>>3)&63, ot = tid>>9;
        int o = ot*16 + (ln&15), c = (ln>>4)*8 + b;
        unsigned short hi, lo; bf16_hilo(dw1[o*32+c], hi, lo);
        W16[6144+tid] = hi; W16[8192+tid] = lo;
    }
    if (tid < 4096){
        int b = tid&7, ln = (tid>>3)&63, f = tid>>9;
        int ot = f>>1, kt = f&1;
        int o = ot*16 + (ln&15), c = kt*32 + (ln>>4)*8 + b;
        unsigned short hi, lo; bf16_hilo(dw2[o*64+c], hi, lo);
        W16[10240+tid] = hi; W16[14336+tid] = lo;
    }
    if (tid < 16384){ int c = tid>>7, o = tid&127; fw2T[tid] = fw2[o*128+c]; }
    if (tid < 8192){ int c = tid>>6, o = tid&63; fw3T[tid] = fw3[o*128+c]; }
}

// ---------------------------------------------------------------- point MLP (both clouds) -> bf16 rows [el4][feat64][pad4]
__global__ __launch_bounds__(256) void mlp3_kernel(
        const float* __restrict__ pc1, const float* __restrict__ el1,
        const float* __restrict__ pc2, const float* __restrict__ el2,
        const float* __restrict__ w1, const float* __restrict__ b1,
        const float* __restrict__ w2, const float* __restrict__ b2,
        const float* __restrict__ w3, const float* __restrict__ b3,
        unsigned short* __restrict__ pf1, unsigned short* __restrict__ pf2){
    __shared__ float W1[96], W2s[1024], W3s[2048], B1[32], B2[32], B3[64];
    const int t = threadIdx.x;
    const int side = (int)(blockIdx.x >= 128);
    const float* pc = side ? pc2 : pc1;
    const float* el = side ? el2 : el1;
    unsigned short* pfeat = side ? pf2 : pf1;
    for (int e=t;e<96;e+=256)   W1[e]=w1[e];
    for (int e=t;e<1024;e+=256) W2s[e]=w2[e];
    for (int e=t;e<2048;e+=256) W3s[e]=w3[e];
    if (t<32){ B1[t]=b1[t]; B2[t]=b2[t]; }
    if (t<64){ B3[t]=b3[t]; }
    __syncthreads();
    const int n = (blockIdx.x & 127)*256 + t;
    const float x0 = pc[n], x1 = pc[NPTS+n], x2 = pc[2*NPTS+n];
    float h1[32];
    #pragma unroll
    for (int o=0;o<32;++o)
        h1[o] = lrelu(B1[o] + W1[o*3]*x0 + W1[o*3+1]*x1 + W1[o*3+2]*x2);
    float h2[32];
    #pragma unroll
    for (int o=0;o<32;++o){
        float a = B2[o];
        #pragma unroll
        for (int c=0;c<32;++c) a += W2s[o*32+c]*h1[c];
        h2[o] = lrelu(a);
    }
    unsigned short* row = pfeat + (size_t)n*72;
    *(ushort4*)row = make_ushort4(bf16r(el[n]), bf16r(el[NPTS+n]),
                                  bf16r(el[2*NPTS+n]), bf16r(el[3*NPTS+n]));
    #pragma unroll
    for (int o4=0;o4<16;++o4){
        float tmp[4];
        #pragma unroll
        for (int q=0;q<4;++q){
            const int o = o4*4+q;
            float a = B3[o];
            #pragma unroll
            for (int c=0;c<32;++c) a += W3s[o*32+c]*h2[c];
            tmp[q] = lrelu(a);
        }
        *(ushort4*)(row + 4 + o4*4) = make_ushort4(bf16r(tmp[0]), bf16r(tmp[1]),
                                                   bf16r(tmp[2]), bf16r(tmp[3]));
    }
    *(ushort4*)(row + 68) = make_ushort4(0,0,0,0);
}

// ---------------------------------------------------------------- bucket build (inverse map)
__global__ __launch_bounds__(256) void bucket_kernel(
        const float* __restrict__ bary1, const float* __restrict__ bary2,
        const int* __restrict__ off1, const int* __restrict__ off2,
        int* __restrict__ cnt,
        int* __restrict__ bnA, float* __restrict__ bvA,
        int* __restrict__ bnB, float* __restrict__ bvB){
    const int tid = blockIdx.x*256 + threadIdx.x;
    const int side = (int)(tid >= 5*NPTS);
    const int p = tid - side*5*NPTS;
    const float b = side ? bary2[p] : bary1[p];
    const int h = side ? off2[p] : off1[p];
    int* bn = side ? bnB : bnA;
    float* bv = side ? bvB : bvA;
    const int slot = atomicAdd(&cnt[side*HL + h], 1);
    if (slot < BCAP){
        bn[h*BCAP + slot] = p & (NPTS-1);
        bv[h*BCAP + slot] = b;
    }
}

// ---------------------------------------------------------------- splat2: gather bf16 pfeat rows -> compact bf16-hi lattice
// lattice row (72 ushorts): [featH 64][elH 4][pad 4]
__global__ __launch_bounds__(256) void splat2_kernel(
        const unsigned short* __restrict__ pf1, const unsigned short* __restrict__ pf2,
        const int* __restrict__ cnt,
        const int* __restrict__ bnA, const float* __restrict__ bvA,
        const int* __restrict__ bnB, const float* __restrict__ bvB,
        unsigned short* __restrict__ latA16, unsigned short* __restrict__ latB16){
    const int gw = (blockIdx.x*256 + threadIdx.x) >> 6;
    const int lane = threadIdx.x & 63;
    const int side = (int)(gw >= HL);
    const int h = gw - side*HL;
    const unsigned short* pfeat = side ? pf2 : pf1;
    const int* bn = side ? bnB : bnA;
    const float* bv = side ? bvB : bvA;
    unsigned short* lat = side ? latB16 : latA16;
    int c = cnt[side*HL + h]; if (c > BCAP) c = BCAP;
    float accF = 0.f, accE = 0.f;
    if (c > 0){
        int n = bn[h*BCAP];
        float b = bv[h*BCAP];
        for (int i=0; i<c; ++i){
            int n2 = 0; float b2 = 0.f;
            if (i+1 < c){ n2 = bn[h*BCAP+i+1]; b2 = bv[h*BCAP+i+1]; }
            const unsigned short* row = pfeat + (size_t)n*72;
            accF += b * us2f(row[4+lane]);
            if (lane < 4) accE += b * us2f(row[lane]);
            n = n2; b = b2;
        }
    }
    lat[(size_t)h*72 + lane] = bf16r(accF);
    if (lane < 4) lat[(size_t)h*72 + 64 + lane] = bf16r(accE);
    if (lane >= 60 && lane < 64) lat[(size_t)h*72 + 8 + lane] = 0;   // pad 68..71
}

// ---------------------------------------------------------------- blur_s: async global_load_lds feat staging (swizzled source), reg-staged el
__global__ __launch_bounds__(256) void blur_s_mfma_kernel(
        const unsigned short* __restrict__ latA16, const unsigned short* __restrict__ latB16,
        const int* __restrict__ nb1, const int* __restrict__ nb2,
        const unsigned short* __restrict__ SW16,
        const float* __restrict__ sb1, const float* __restrict__ sb2,
        unsigned short* __restrict__ lat2b, unsigned short* __restrict__ catHL){
    __shared__ __align__(16) unsigned short GH[2][2048];
    __shared__ __align__(16) unsigned short EH[2048];
    __shared__ int sidx[NNB][32];
    const int side = (int)(blockIdx.x >= 1024);
    const unsigned short* lat = side ? latB16 : latA16;
    const int* nb = side ? nb2 : nb1;
    const int t = threadIdx.x;
    const int hb = (blockIdx.x & 1023)*32;
    const int w = t>>6, lane = t&63;
    const int l15 = lane&15, lg = lane>>4;
    const int rowS = t>>3, qS = t&7;
    const int srcOff = (qS ^ (rowS&7))*8;   // swizzle applied at the SOURCE
    for (int e=t; e<NNB*32; e+=256) sidx[e>>5][e&31] = nb[(e>>5)*HL + hb + (e&31)];
    {
        const uint4 z4 = {0,0,0,0};
        *(uint4*)(EH + t*8) = z4;
    }
    __syncthreads();
#define FSTAGE(NN_,BUF_) { \
        const int g_ = sidx[NN_][rowS]; \
        async_cp16(lat + (size_t)g_*72 + srcOff, GH[BUF_] + w*512); }
#define ELOAD(Re_,NN_) { \
        if (t < 32) Re_ = *(const uint2*)(lat + (size_t)sidx[NN_][t]*72 + 64); }
#define EWRITE(Re_,NN_) { \
        if (t < 32){ \
            const int d_ = t*64 + ((((NN_)>>1) ^ (t&7))*8) + (((NN_)&1)*4); \
            *(uint2*)(EH + d_) = Re_; } }
#define SCOMPUTE(NN_,BUF_) { \
        _Pragma("unroll") \
        for (int kt=0; kt<2; ++kt){ \
            s16x8 BH[2]; \
            _Pragma("unroll") \
            for (int ht=0; ht<2; ++ht){ \
                const int h_ = ht*16 + l15; \
                const int qq_ = kt*4 + lg; \
                const int d_ = h_*64 + ((qq_ ^ (h_&7))*8); \
                BH[ht] = *(const s16x8*)(GH[BUF_] + d_); } \
            const int f_ = (NN_)*2 + kt; \
            const s16x8 AH = *(const s16x8*)(SW16 + (f_*4+w)*512 + lane*8); \
            const s16x8 AL = *(const s16x8*)(SW16 + 61440 + (f_*4+w)*512 + lane*8); \
            _Pragma("unroll") \
            for (int ht=0; ht<2; ++ht){ \
                acc[ht] = __builtin_amdgcn_mfma_f32_16x16x32_bf16(AH, BH[ht], acc[ht], 0,0,0); \
                acc[ht] = __builtin_amdgcn_mfma_f32_16x16x32_bf16(AL, BH[ht], acc[ht], 0,0,0); } } }
    uint2 Ae, Be;
    FSTAGE(0,0)
    ELOAD(Ae,0)
    __syncthreads();
    const f32x4 z = {0.f,0.f,0.f,0.f};
    f32x4 acc[2] = {z,z};
    #pragma unroll 1
    for (int nn=0; nn<NNB; ++nn){
        const int cur = nn&1;
        if (nn+1 < NNB) FSTAGE((nn+1),(cur^1))
        EWRITE(Ae,nn)
        if (nn+1 < NNB) ELOAD(Be,(nn+1))
        SCOMPUTE(nn,cur)
        __syncthreads();
        Ae = Be;
    }
#undef FSTAGE
#undef ELOAD
#undef EWRITE
#undef SCOMPUTE
    // el GEMM (K=64 packed across nn, hi-only B)
    #pragma unroll
    for (int kt2=0; kt2<2; ++kt2){
        s16x8 BH[2];
        #pragma unroll
        for (int ht=0; ht<2; ++ht){
            const int h = ht*16 + l15;
            const int qq = kt2*4 + lg;
            const int d = h*64 + ((qq ^ (h&7))*8);
            BH[ht] = *(const s16x8*)(EH + d);
        }
        const s16x8 AH = *(const s16x8*)(SW16 + 122880 + (kt2*4+w)*512 + lane*8);
        const s16x8 AL = *(const s16x8*)(SW16 + 126976 + (kt2*4+w)*512 + lane*8);
        #pragma unroll
        for (int ht=0; ht<2; ++ht){
            acc[ht] = __builtin_amdgcn_mfma_f32_16x16x32_bf16(AH, BH[ht], acc[ht], 0,0,0);
            acc[ht] = __builtin_amdgcn_mfma_f32_16x16x32_bf16(AL, BH[ht], acc[ht], 0,0,0);
        }
    }
    // T = lrelu(acc + sb1) -> hi in GH[0], lo in GH[1]
    {
        const int o0 = w*16 + lg*4;
        float bs1v[4];
        #pragma unroll
        for (int j=0;j<4;++j) bs1v[j] = sb1[o0+j];
        const int q16 = o0>>3;
        #pragma unroll
        for (int ht=0; ht<2; ++ht){
            const int h = ht*16 + l15;
            unsigned short th[4], tl[4];
            #pragma unroll
            for (int j=0;j<4;++j) bf16_hilo(lrelu(acc[ht][j] + bs1v[j]), th[j], tl[j]);
            const int d = h*64 + ((q16 ^ (h&7))*8) + (o0&7);
            *(ushort4*)(GH[0] + d) = make_ushort4(th[0],th[1],th[2],th[3]);
            *(ushort4*)(GH[1] + d) = make_ushort4(tl[0],tl[1],tl[2],tl[3]);
        }
    }
    __syncthreads();
    f32x4 acc2[2] = {z,z};
    #pragma unroll
    for (int kt=0; kt<2; ++kt){
        s16x8 BH[2], BL[2];
        #pragma unroll
        for (int ht=0; ht<2; ++ht){
            const int h = ht*16 + l15;
            const int qq = kt*4 + lg;
            const int d = h*64 + ((qq ^ (h&7))*8);
            BH[ht] = *(const s16x8*)(GH[0] + d);
            BL[ht] = *(const s16x8*)(GH[1] + d);
        }
        const s16x8 AH = *(const s16x8*)(SW16 + 131072 + (kt*4+w)*512 + lane*8);
        const s16x8 AL = *(const s16x8*)(SW16 + 135168 + (kt*4+w)*512 + lane*8);
        #pragma unroll
        for (int ht=0; ht<2; ++ht){
            acc2[ht] = __builtin_amdgcn_mfma_f32_16x16x32_bf16(AH, BH[ht], acc2[ht], 0,0,0);
            acc2[ht] = __builtin_amdgcn_mfma_f32_16x16x32_bf16(AH, BL[ht], acc2[ht], 0,0,0);
            acc2[ht] = __builtin_amdgcn_mfma_f32_16x16x32_bf16(AL, BH[ht], acc2[ht], 0,0,0);
        }
    }
    {
        const int o0 = w*16 + lg*4;
        float bs2v[4];
        #pragma unroll
        for (int j=0;j<4;++j) bs2v[j] = sb2[o0+j];
        #pragma unroll
        for (int ht=0; ht<2; ++ht){
            const int h = hb + ht*16 + l15;
            float v0 = lrelu(acc2[ht][0]+bs2v[0]), v1 = lrelu(acc2[ht][1]+bs2v[1]);
            float v2 = lrelu(acc2[ht][2]+bs2v[2]), v3 = lrelu(acc2[ht][3]+bs2v[3]);
            if (side){
                *(ushort4*)(lat2b + (size_t)h*64 + o0) =
                    make_ushort4(bf16r(v0), bf16r(v1), bf16r(v2), bf16r(v3));
            } else {
                unsigned short th[4], tl[4];
                bf16_hilo(v0, th[0], tl[0]); bf16_hilo(v1, th[1], tl[1]);
                bf16_hilo(v2, th[2], tl[2]); bf16_hilo(v3, th[3], tl[3]);
                *(ushort4*)(catHL + (size_t)h*256 + o0) = make_ushort4(th[0],th[1],th[2],th[3]);
                *(ushort4*)(catHL + (size_t)h*256 + 128 + o0) = make_ushort4(tl[0],tl[1],tl[2],tl[3]);
            }
        }
    }
}

// ---------------------------------------------------------------- corr step (bf16-hi gather, P quantized to bf16, deep prefetch)
__device__ __forceinline__ void corr_step(
        uint4& Gl, uint4& Gh, int& idxq, int knext,
        const unsigned short* __restrict__ lat2b, const int* __restrict__ ci, int hcol, int lg,
        const float* l1f, const float* cb1r, const float* cb2r,
        const s16x8 (&C1H)[2][2], const s16x8 (&C1L)[2][2],
        const s16x8 (&C2H)[2], const s16x8 (&C2L)[2],
        int sel, int srcA, int srcB, float* agg){
    const f32x4 z = {0.f,0.f,0.f,0.f};
    float p[16];
    p[0]=l1f[0]*blo(Gl.x);  p[1]=l1f[1]*bhi(Gl.x);
    p[2]=l1f[2]*blo(Gl.y);  p[3]=l1f[3]*bhi(Gl.y);
    p[4]=l1f[4]*blo(Gl.z);  p[5]=l1f[5]*bhi(Gl.z);
    p[6]=l1f[6]*blo(Gl.w);  p[7]=l1f[7]*bhi(Gl.w);
    p[8]=l1f[8]*blo(Gh.x);  p[9]=l1f[9]*bhi(Gh.x);
    p[10]=l1f[10]*blo(Gh.y); p[11]=l1f[11]*bhi(Gh.y);
    p[12]=l1f[12]*blo(Gh.z); p[13]=l1f[13]*bhi(Gh.z);
    p[14]=l1f[14]*blo(Gh.w); p[15]=l1f[15]*bhi(Gh.w);
    {
        const unsigned short* r = lat2b + (size_t)idxq*64 + lg*8;
        Gl = *(const uint4*)r;
        Gh = *(const uint4*)(r + 32);
    }
    idxq = ci[knext*HL + hcol];
    pk8 BH[2];
    #pragma unroll
    for (int kt=0; kt<2; ++kt)
        #pragma unroll
        for (int q=0; q<4; ++q)
            BH[kt].u[q] = pk2(bf16r(p[kt*8+2*q]), bf16r(p[kt*8+2*q+1]));
    f32x4 a1[2] = {z, z};
    #pragma unroll
    for (int kt=0; kt<2; ++kt){
        a1[0] = __builtin_amdgcn_mfma_f32_16x16x32_bf16(C1H[0][kt], BH[kt].v, a1[0], 0,0,0);
        a1[1] = __builtin_amdgcn_mfma_f32_16x16x32_bf16(C1H[1][kt], BH[kt].v, a1[1], 0,0,0);
        a1[0] = __builtin_amdgcn_mfma_f32_16x16x32_bf16(C1L[0][kt], BH[kt].v, a1[0], 0,0,0);
        a1[1] = __builtin_amdgcn_mfma_f32_16x16x32_bf16(C1L[1][kt], BH[kt].v, a1[1], 0,0,0);
    }
    unsigned mh[2][2], ml[2][2];
    #pragma unroll
    for (int ot=0; ot<2; ++ot)
        #pragma unroll
        for (int j=0; j<2; ++j)
            fsplit2(lrelu(a1[ot][2*j]   + cb1r[ot*4+2*j]),
                    lrelu(a1[ot][2*j+1] + cb1r[ot*4+2*j+1]), mh[ot][j], ml[ot][j]);
    pk8 B2H = shuf32(mh[0], mh[1], sel, srcA, srcB);
    pk8 B2L = shuf32(ml[0], ml[1], sel, srcA, srcB);
    f32x4 a2[2] = {z, z};
    a2[0] = __builtin_amdgcn_mfma_f32_16x16x32_bf16(C2H[0], B2H.v, a2[0], 0,0,0);
    a2[1] = __builtin_amdgcn_mfma_f32_16x16x32_bf16(C2H[1], B2H.v, a2[1], 0,0,0);
    a2[0] = __builtin_amdgcn_mfma_f32_16x16x32_bf16(C2H[0], B2L.v, a2[0], 0,0,0);
    a2[1] = __builtin_amdgcn_mfma_f32_16x16x32_bf16(C2H[1], B2L.v, a2[1], 0,0,0);
    a2[0] = __builtin_amdgcn_mfma_f32_16x16x32_bf16(C2L[0], B2H.v, a2[0], 0,0,0);
    a2[1] = __builtin_amdgcn_mfma_f32_16x16x32_bf16(C2L[1], B2H.v, a2[1], 0,0,0);
    #pragma unroll
    for (int i=0;i<8;++i)
        agg[i] += lrelu(a2[i>>2][i&3] + cb2r[i]);
}

// ---------------------------------------------------------------- corr + d-MLP, split-K + deep prefetch
__global__ __launch_bounds__(256, 4) void corr_mfma_kernel(
        const unsigned short* __restrict__ lat2b, const int* __restrict__ ci,
        const unsigned short* __restrict__ W16,
        const float* __restrict__ cb1, const float* __restrict__ cb2,
        const float* __restrict__ db1, const float* __restrict__ db2,
        unsigned short* __restrict__ catHL){
    __shared__ float AGG[2][64][8];
    const int t = threadIdx.x;
    const int lane = t & 63;
    const int l15 = lane & 15, lg = lane >> 4;
    const int w = t >> 6;
    const int hgrp = w >> 1, khalf = w & 1;
    const int hcol = blockIdx.x*32 + hgrp*16 + l15;
    const int srcA = (l15 + ((lg&1)*32)) * 4;
    const int srcB = srcA + 64;
    const int sel = (lg>>1) & 1;

    s16x8 C1H[2][2], C1L[2][2], C2H[2], C2L[2];
    #pragma unroll
    for (int ot=0; ot<2; ++ot){
        #pragma unroll
        for (int kt=0; kt<2; ++kt){
            C1H[ot][kt] = *(const s16x8*)(W16 + (ot*2+kt)*512 + lane*8);
            C1L[ot][kt] = *(const s16x8*)(W16 + 2048 + (ot*2+kt)*512 + lane*8);
        }
        C2H[ot] = *(const s16x8*)(W16 + 4096 + ot*512 + lane*8);
        C2L[ot] = *(const s16x8*)(W16 + 5120 + ot*512 + lane*8);
    }
    float l1f[16];
    {
        const unsigned short* hr = catHL + (size_t)hcol*256;
        const unsigned short* lr = hr + 128;
        const ushort4 h0 = *(const ushort4*)(hr + lg*8);
        const ushort4 h1 = *(const ushort4*)(hr + lg*8 + 4);
        const ushort4 h2 = *(const ushort4*)(hr + 32 + lg*8);
        const ushort4 h3 = *(const ushort4*)(hr + 32 + lg*8 + 4);
        const ushort4 l0 = *(const ushort4*)(lr + lg*8);
        const ushort4 l1 = *(const ushort4*)(lr + lg*8 + 4);
        const ushort4 l2 = *(const ushort4*)(lr + 32 + lg*8);
        const ushort4 l3 = *(const ushort4*)(lr + 32 + lg*8 + 4);
        l1f[0]=bf2f(h0.x,l0.x); l1f[1]=bf2f(h0.y,l0.y); l1f[2]=bf2f(h0.z,l0.z); l1f[3]=bf2f(h0.w,l0.w);
        l1f[4]=bf2f(h1.x,l1.x); l1f[5]=bf2f(h1.y,l1.y); l1f[6]=bf2f(h1.z,l1.z); l1f[7]=bf2f(h1.w,l1.w);
        l1f[8]=bf2f(h2.x,l2.x); l1f[9]=bf2f(h2.y,l2.y); l1f[10]=bf2f(h2.z,l2.z); l1f[11]=bf2f(h2.w,l2.w);
        l1f[12]=bf2f(h3.x,l3.x); l1f[13]=bf2f(h3.y,l3.y); l1f[14]=bf2f(h3.z,l3.z); l1f[15]=bf2f(h3.w,l3.w);
    }
    float cb1r[8], cb2r[8];
    #pragma unroll
    for (int i=0;i<8;++i){
        cb1r[i] = cb1[(i>>2)*16 + lg*4 + (i&3)];
        cb2r[i] = cb2[(i>>2)*16 + lg*4 + (i&3)];
    }
    float agg[8] = {};
    const f32x4 z = {0.f,0.f,0.f,0.f};

    const int kbeg = khalf*16;
    int idx0 = ci[(kbeg+0)*HL + hcol];
    int idx1 = ci[(kbeg+1)*HL + hcol];
    uint4 GaL,GaH, GbL,GbH;
    {
        const unsigned short* r = lat2b + (size_t)idx0*64 + lg*8;
        GaL = *(const uint4*)r;  GaH = *(const uint4*)(r + 32);
    }
    {
        const unsigned short* r = lat2b + (size_t)idx1*64 + lg*8;
        GbL = *(const uint4*)r;  GbH = *(const uint4*)(r + 32);
    }
    idx0 = ci[(kbeg+2)*HL + hcol];
    idx1 = ci[(kbeg+3)*HL + hcol];
    #pragma unroll 1
    for (int k2=0; k2<8; ++k2){
        const int ke = kbeg + 2*k2;
        corr_step(GaL,GaH, idx0, min(ke+4, 31), lat2b, ci, hcol, lg,
                  l1f, cb1r, cb2r, C1H, C1L, C2H, C2L, sel, srcA, srcB, agg);
        corr_step(GbL,GbH, idx1, min(ke+5, 31), lat2b, ci, hcol, lg,
                  l1f, cb1r, cb2r, C1H, C1L, C2H, C2L, sel, srcA, srcB, agg);
    }
    if (khalf){
        #pragma unroll
        for (int i=0;i<8;++i) AGG[hgrp][lane][i] = agg[i];
    }
    __syncthreads();
    if (khalf) return;
    #pragma unroll
    for (int i=0;i<8;++i) agg[i] = (agg[i] + AGG[hgrp][lane][i]) * (1.0f/32.0f);
    unsigned agH[2][2], agL[2][2];
    #pragma unroll
    for (int ot=0; ot<2; ++ot)
        #pragma unroll
        for (int j=0; j<2; ++j)
            fsplit2(agg[ot*4+2*j], agg[ot*4+2*j+1], agH[ot][j], agL[ot][j]);
    pk8 B3H = shuf32(agH[0], agH[1], sel, srcA, srcB);
    pk8 B3L = shuf32(agL[0], agL[1], sel, srcA, srcB);
    float db1r[16], db2r[16];
    #pragma unroll
    for (int i=0;i<16;++i){
        db1r[i] = db1[(i>>2)*16 + lg*4 + (i&3)];
        db2r[i] = db2[(i>>2)*16 + lg*4 + (i&3)];
    }
    unsigned d1H[4][2], d1L[4][2];
    #pragma unroll
    for (int ot=0; ot<4; ++ot){
        s16x8 AH = *(const s16x8*)(W16 + 6144 + ot*512 + lane*8);
        s16x8 AL = *(const s16x8*)(W16 + 8192 + ot*512 + lane*8);
        f32x4 a3 = z;
        a3 = __builtin_amdgcn_mfma_f32_16x16x32_bf16(AH, B3H.v, a3, 0,0,0);
        a3 = __builtin_amdgcn_mfma_f32_16x16x32_bf16(AH, B3L.v, a3, 0,0,0);
        a3 = __builtin_amdgcn_mfma_f32_16x16x32_bf16(AL, B3H.v, a3, 0,0,0);
        #pragma unroll
        for (int j=0;j<2;++j)
            fsplit2(lrelu(a3[2*j]   + db1r[ot*4+2*j]),
                    lrelu(a3[2*j+1] + db1r[ot*4+2*j+1]), d1H[ot][j], d1L[ot][j]);
    }
    f32x4 a4[4] = {z,z,z,z};
    #pragma unroll
    for (int kt=0; kt<2; ++kt){
        pk8 B4H = shuf32(d1H[kt*2], d1H[kt*2+1], sel, srcA, srcB);
        pk8 B4L = shuf32(d1L[kt*2], d1L[kt*2+1], sel, srcA, srcB);
        #pragma unroll
        for (int ot=0; ot<4; ++ot){
            s16x8 AH = *(const s16x8*)(W16 + 10240 + (ot*2+kt)*512 + lane*8);
            s16x8 AL = *(const s16x8*)(W16 + 14336 + (ot*2+kt)*512 + lane*8);
            a4[ot] = __builtin_amdgcn_mfma_f32_16x16x32_bf16(AH, B4H.v, a4[ot], 0,0,0);
            a4[ot] = __builtin_amdgcn_mfma_f32_16x16x32_bf16(AH, B4L.v, a4[ot], 0,0,0);
            a4[ot] = __builtin_amdgcn_mfma_f32_16x16x32_bf16(AL, B4H.v, a4[ot], 0,0,0);
        }
    }
    unsigned short* dH = catHL + (size_t)hcol*256 + 64;
    unsigned short* dL = catHL + (size_t)hcol*256 + 192;
    #pragma unroll
    for (int ot=0; ot<4; ++ot){
        float v0 = lrelu(a4[ot][0]+db2r[ot*4+0]), v1 = lrelu(a4[ot][1]+db2r[ot*4+1]);
        float v2 = lrelu(a4[ot][2]+db2r[ot*4+2]), v3 = lrelu(a4[ot][3]+db2r[ot*4+3]);
        unsigned short th[4], tl[4];
        fsplit1(v0, th[0], tl[0]); fsplit1(v1, th[1], tl[1]);
        fsplit1(v2, th[2], tl[2]); fsplit1(v3, th[3], tl[3]);
        *(ushort4*)(dH + ot*16 + lg*4) = make_ushort4(th[0],th[1],th[2],th[3]);
        *(ushort4*)(dL + ot*16 + lg*4) = make_ushort4(tl[0],tl[1],tl[2],tl[3]);
    }
}

// ---------------------------------------------------------------- blur_p: async global_load_lds staging (swizzled source, linear LDS)
__global__ __launch_bounds__(512) void blur_p_mfma_kernel(
        const unsigned short* __restrict__ catHL,
        const int* __restrict__ nb,
        const unsigned short* __restrict__ pw1fH, const unsigned short* __restrict__ pw1fL,
        const float* __restrict__ pb1,
        const unsigned short* __restrict__ pw2fH, const unsigned short* __restrict__ pw2fL,
        const float* __restrict__ pb2,
        unsigned short* __restrict__ p16){
    __shared__ __align__(16) unsigned short GH[2][4096];
    __shared__ int sidx[NNB][32];
    const int t = threadIdx.x;
    const int hb = blockIdx.x*32;
    const int w = t>>6, lane = t&63;
    const int l15 = lane&15, lg = lane>>4;
    const int row = t>>4, q = t&15;
    const int srcOff = (q ^ (row&7))*8;       // swizzle applied at the SOURCE
    for (int e=t; e<NNB*32; e+=512) sidx[e>>5][e&31] = nb[(e>>5)*HL + hb + (e&31)];
    const f32x4 z = {0.f,0.f,0.f,0.f};
    f32x4 acc1[2] = {z,z};
    __syncthreads();
#define PSTAGE(NN_,BUF_) { \
        const int g_ = sidx[NN_][row]; \
        async_cp16(catHL + (size_t)g_*256 + srcOff, GH[BUF_] + w*512); }
#define PCOMPUTE(NN_,BUF_) { \
        _Pragma("unroll") \
        for (int kt=0; kt<4; ++kt){ \
            s16x8 BH[2]; \
            _Pragma("unroll") \
            for (int ht=0; ht<2; ++ht){ \
                const int h_ = ht*16 + l15; \
                const int qq_ = kt*4 + lg; \
                const int d_ = h_*128 + ((qq_ ^ (h_&7))*8); \
                BH[ht] = *(const s16x8*)(GH[BUF_] + d_); } \
            const size_t fo_ = ((size_t)(((NN_)*4 + kt)*8 + w))*512 + lane*8; \
            const s16x8 AH = *(const s16x8*)(pw1fH + fo_); \
            const s16x8 AL = *(const s16x8*)(pw1fL + fo_); \
            _Pragma("unroll") \
            for (int ht=0; ht<2; ++ht){ \
                acc1[ht] = __builtin_amdgcn_mfma_f32_16x16x32_bf16(AH, BH[ht], acc1[ht], 0,0,0); \
                acc1[ht] = __builtin_amdgcn_mfma_f32_16x16x32_bf16(AL, BH[ht], acc1[ht], 0,0,0); } } }
    PSTAGE(0,0)
    __syncthreads();
    #pragma unroll 1
    for (int nn=0; nn<NNB; ++nn){
        const int cur = nn&1;
        if (nn+1 < NNB) PSTAGE((nn+1),(cur^1))
        PCOMPUTE(nn,cur)
        __syncthreads();
    }
#undef PSTAGE
#undef PCOMPUTE
    // epilogue 1: T = lrelu(acc1 + pb1); hi -> GH[0], lo -> GH[1]
    {
        const int o0 = w*16 + lg*4;
        const float b0 = pb1[o0], b1v = pb1[o0+1], b2v = pb1[o0+2], b3v = pb1[o0+3];
        const int qc = o0>>3;
        #pragma unroll
        for (int ht=0; ht<2; ++ht){
            const int h = ht*16 + l15;
            unsigned short th[4], tl[4];
            bf16_hilo(lrelu(acc1[ht][0] + b0), th[0], tl[0]);
            bf16_hilo(lrelu(acc1[ht][1] + b1v), th[1], tl[1]);
            bf16_hilo(lrelu(acc1[ht][2] + b2v), th[2], tl[2]);
            bf16_hilo(lrelu(acc1[ht][3] + b3v), th[3], tl[3]);
            const int d = h*128 + ((qc ^ (h&7))*8) + (o0&7);
            *(ushort4*)(GH[0] + d) = make_ushort4(th[0],th[1],th[2],th[3]);
            *(ushort4*)(GH[1] + d) = make_ushort4(tl[0],tl[1],tl[2],tl[3]);
        }
    }
    __syncthreads();
    f32x4 acc2[2] = {z,z};
    #pragma unroll
    for (int kt=0; kt<4; ++kt){
        s16x8 BH[2], BL[2];
        #pragma unroll
        for (int ht=0; ht<2; ++ht){
            const int h = ht*16 + l15;
            const int qq = kt*4 + lg;
            const int d = h*128 + ((qq ^ (h&7))*8);
            BH[ht] = *(const s16x8*)(GH[0] + d);
            BL[ht] = *(const s16x8*)(GH[1] + d);
        }
        const size_t fo = ((size_t)(kt*8 + w))*512 + lane*8;
        const s16x8 AH = *(const s16x8*)(pw2fH + fo);
        const s16x8 AL = *(const s16x8*)(pw2fL + fo);
        #pragma unroll
        for (int ht=0; ht<2; ++ht){
            acc2[ht] = __builtin_amdgcn_mfma_f32_16x16x32_bf16(AH, BH[ht], acc2[ht], 0,0,0);
            acc2[ht] = __builtin_amdgcn_mfma_f32_16x16x32_bf16(AH, BL[ht], acc2[ht], 0,0,0);
            acc2[ht] = __builtin_amdgcn_mfma_f32_16x16x32_bf16(AL, BH[ht], acc2[ht], 0,0,0);
        }
    }
    {
        const int o0 = w*16 + lg*4;
        const float b0 = pb2[o0], b1v = pb2[o0+1], b2v = pb2[o0+2], b3v = pb2[o0+3];
        #pragma unroll
        for (int ht=0; ht<2; ++ht){
            const int h = hb + ht*16 + l15;
            *(ushort4*)(p16 + (size_t)h*128 + o0) = make_ushort4(
                bf16r(lrelu(acc2[ht][0] + b0)),  bf16r(lrelu(acc2[ht][1] + b1v)),
                bf16r(lrelu(acc2[ht][2] + b2v)), bf16r(lrelu(acc2[ht][3] + b3v)));
        }
    }
}

// ---------------------------------------------------------------- head: slice (bf16 p) + 128->128->64->3
__global__ __launch_bounds__(256) void head_kernel(
        const unsigned short* __restrict__ p16, const float* __restrict__ bary, const int* __restrict__ off,
        const float* __restrict__ fw2T, const float* __restrict__ fb2,
        const float* __restrict__ fw3T, const float* __restrict__ fb3,
        const float* __restrict__ fw4, const float* __restrict__ fb4,
        float* __restrict__ out){
    __shared__ __align__(16) float S[8704];
    __shared__ __align__(16) float WW[8192];
    __shared__ float SB[5][64];
    __shared__ int   SO[5][64];
    const int t = threadIdx.x;
    const int pb = blockIdx.x*64;
    const int oq8 = t>>4, pq = t&15;
    if (t<64){
        #pragma unroll
        for (int j=0;j<5;++j){ SB[j][t]=bary[j*NPTS+pb+t]; SO[j][t]=off[j*NPTS+pb+t]; }
    }
    __syncthreads();
    // stage S[c][pt]: 16 threads/row x 8 ch, 4 row-passes
    {
        const int qh = t & 15, rg = t >> 4;
        #pragma unroll
        for (int i=0;i<4;++i){
            const int row = rg + 16*i;
            float sa[8] = {0.f,0.f,0.f,0.f,0.f,0.f,0.f,0.f};
            #pragma unroll
            for (int j=0;j<5;++j){
                const uint4 v = *(const uint4*)(p16 + (size_t)SO[j][row]*128 + qh*8);
                const float b = SB[j][row];
                sa[0]+=b*blo(v.x); sa[1]+=b*bhi(v.x);
                sa[2]+=b*blo(v.y); sa[3]+=b*bhi(v.y);
                sa[4]+=b*blo(v.z); sa[5]+=b*bhi(v.z);
                sa[6]+=b*blo(v.w); sa[7]+=b*bhi(v.w);
            }
            #pragma unroll
            for (int c=0;c<8;++c) S[(qh*8+c)*68 + row] = sa[c];
        }
    }
    float acc1[8][4] = {};
    #pragma unroll 1
    for (int hf=0;hf<2;++hf){
        if (hf==1) __syncthreads();
        for (int e=t;e<2048;e+=256)
            *(float4*)(WW + e*4) = *(const float4*)(fw2T + hf*8192 + e*4);
        __syncthreads();
        #pragma unroll 4
        for (int c=0;c<64;++c){
            const float4 a4 = *(const float4*)(S + (hf*64+c)*68 + pq*4);
            const float4 wa = *(const float4*)(WW + c*128 + oq8*8);
            const float4 wb = *(const float4*)(WW + c*128 + oq8*8 + 4);
            const float av[4]={a4.x,a4.y,a4.z,a4.w};
            const float wv[8]={wa.x,wa.y,wa.z,wa.w,wb.x,wb.y,wb.z,wb.w};
            #pragma unroll
            for (int i=0;i<8;++i)
                #pragma unroll
                for (int j=0;j<4;++j)
                    acc1[i][j] = fmaf(wv[i], av[j], acc1[i][j]);
        }
    }
    __syncthreads();
    float bf2v[8];
    #pragma unroll
    for (int i=0;i<8;++i) bf2v[i]=fb2[oq8*8+i];
    #pragma unroll
    for (int i=0;i<8;++i){
        const int o = oq8*8+i;
        float4 v = make_float4(lrelu(acc1[i][0]+bf2v[i]), lrelu(acc1[i][1]+bf2v[i]),
                               lrelu(acc1[i][2]+bf2v[i]), lrelu(acc1[i][3]+bf2v[i]));
        *(float4*)(S + o*68 + pq*4) = v;
    }
    for (int e=t;e<2048;e+=256)
        *(float4*)(WW + e*4) = *(const float4*)(fw3T + e*4);
    __syncthreads();
    const int od = t>>4;
    float bf3[4];
    #pragma unroll
    for (int i=0;i<4;++i) bf3[i]=fb3[od*4+i];
    float a2[4][4] = {};
    #pragma unroll 4
    for (int c=0;c<128;++c){
        const float4 a4 = *(const float4*)(S + c*68 + pq*4);
        const float4 w4 = *(const float4*)(WW + c*64 + od*4);
        const float av[4]={a4.x,a4.y,a4.z,a4.w};
        const float wv[4]={w4.x,w4.y,w4.z,w4.w};
        #pragma unroll
        for (int i=0;i<4;++i)
            #pragma unroll
            for (int j=0;j<4;++j)
                a2[i][j] = fmaf(wv[i], av[j], a2[i][j]);
    }
    __syncthreads();
    #pragma unroll
    for (int i=0;i<4;++i){
        float4 v = make_float4(lrelu(a2[i][0]+bf3[i]), lrelu(a2[i][1]+bf3[i]),
                               lrelu(a2[i][2]+bf3[i]), lrelu(a2[i][3]+bf3[i]));
        *(float4*)(S + (od*4+i)*68 + pq*4) = v;
    }
    __syncthreads();
    if (t < 192){
        const int r = t>>6, pp = t&63;
        float a = fb4[r];
        #pragma unroll 8
        for (int c=0;c<64;++c) a += fw4[r*64+c]*S[c*68+pp];
        out[r*NPTS + pb + pp] = a;
    }
}

// ================================================================ launch
extern "C" void kernel_launch(void* const* d_in, const int* in_sizes, int n_in,
                              void* d_out, int out_size, void* d_ws, size_t ws_size,
                              hipStream_t stream){
    const float* pc1   = (const float*)d_in[0];
    const float* pc2   = (const float*)d_in[1];
    const float* el1   = (const float*)d_in[2];
    const float* el2   = (const float*)d_in[3];
    const float* bary1 = (const float*)d_in[4];
    const float* bary2 = (const float*)d_in[5];
    const int*   off1  = (const int*)d_in[6];
    const int*   off2  = (const int*)d_in[7];
    const int*   nb1   = (const int*)d_in[8];
    const int*   nb2   = (const int*)d_in[9];
    const int*   ci    = (const int*)d_in[10];
    const float* w1    = (const float*)d_in[11];
    const float* b1    = (const float*)d_in[12];
    const float* w2    = (const float*)d_in[13];
    const float* b2    = (const float*)d_in[14];
    const float* w3    = (const float*)d_in[15];
    const float* b3    = (const float*)d_in[16];
    const float* sw1   = (const float*)d_in[17];
    const float* sb1   = (const float*)d_in[18];
    const float* sw2   = (const float*)d_in[19];
    const float* sb2   = (const float*)d_in[20];
    const float* cw1   = (const float*)d_in[21];
    const float* cb1   = (const float*)d_in[22];
    const float* cw2   = (const float*)d_in[23];
    const float* cb2   = (const float*)d_in[24];
    const float* dw1   = (const float*)d_in[25];
    const float* db1   = (const float*)d_in[26];
    const float* dw2   = (const float*)d_in[27];
    const float* db2   = (const float*)d_in[28];
    const float* pw1   = (const float*)d_in[29];
    const float* pb1   = (const float*)d_in[30];
    const float* pw2   = (const float*)d_in[31];
    const float* pb2   = (const float*)d_in[32];
    const float* fw2   = (const float*)d_in[33];
    const float* fb2   = (const float*)d_in[34];
    const float* fw3   = (const float*)d_in[35];
    const float* fb3   = (const float*)d_in[36];
    const float* fw4   = (const float*)d_in[37];
    const float* fb4   = (const float*)d_in[38];
    float* out = (float*)d_out;

    float* ws    = (float*)d_ws;
    float* pf1f  = ws;                    // 2228224 floats region ; pfeat bf16 + later p16
    float* pf2f  = pf1f  + 2228224;
    float* bkt   = pf2f  + 2228224;       // 4456448 (buckets) ; later catHL
    float* lat16 = bkt   + 4456448;       // compact hi lattice: 2*HL*72 ushorts
    float* lat2f = lat16 + 4456448;       // lat2b bf16 (HL*64 ushorts)
    float* pw1fS = lat2f + 2097152;       // 245760
    float* SW16f = pw1fS + 245760;        // 69632
    float* W16f  = SW16f + 69632;         // 9216
    float* pw2fS = W16f  + 9216;          // 16384
    float* fw2T  = pw2fS + 16384;         // 16384
    float* fw3T  = fw2T  + 16384;         // 8192
    float* cntf  = fw3T  + 8192;          // 16384 ints

    unsigned short* pw1fH = (unsigned short*)pw1fS;
    unsigned short* pw1fL = pw1fH + 245760;
    unsigned short* SW16  = (unsigned short*)SW16f;
    unsigned short* W16   = (unsigned short*)W16f;
    unsigned short* pw2fH = (unsigned short*)pw2fS;
    unsigned short* pw2fL = pw2fH + 16384;
    int*   cnt  = (int*)cntf;
    int*   bnA  = (int*)bkt;
    float* bvA  = bkt + (size_t)HL*BCAP;
    int*   bnB  = (int*)(bkt + 2228224);
    float* bvB  = bkt + 2228224 + (size_t)HL*BCAP;
    unsigned short* pf1 = (unsigned short*)pf1f;         // NPTS*72 bf16
    unsigned short* pf2 = (unsigned short*)pf2f;
    unsigned short* latA16 = (unsigned short*)lat16;     // HL*72 compact hi
    unsigned short* latB16 = latA16 + (size_t)HL*72;
    unsigned short* catHL  = (unsigned short*)bkt;       // HL*256 (buckets dead)
    unsigned short* lat2b  = (unsigned short*)lat2f;     // HL*64 bf16-hi
    unsigned short* p16    = (unsigned short*)pf1f;      // HL*128 bf16 (pfeat dead)

    init_kernel<<<960, 256, 0, stream>>>(cnt,
                                         sw1, pw1, sw2, cw1, cw2, dw1, dw2, pw2, fw2, fw3,
                                         SW16, pw1fH, pw1fL, W16,
                                         pw2fH, pw2fL, fw2T, fw3T);

    mlp3_kernel<<<256, 256, 0, stream>>>(pc1, el1, pc2, el2, w1,b1,w2,b2,w3,b3, pf1, pf2);

    bucket_kernel<<<1280, 256, 0, stream>>>(bary1, bary2, off1, off2, cnt,
                                            bnA, bvA, bnB, bvB);

    splat2_kernel<<<16384, 256, 0, stream>>>(pf1, pf2, cnt, bnA, bvA, bnB, bvB,
                                             latA16, latB16);

    blur_s_mfma_kernel<<<2048, 256, 0, stream>>>(latA16, latB16, nb1, nb2, SW16, sb1, sb2,
                                                 lat2b, catHL);

    corr_mfma_kernel<<<1024, 256, 0, stream>>>(lat2b, ci, W16, cb1, cb2, db1, db2, catHL);

    blur_p_mfma_kernel<<<1024, 512, 0, stream>>>(catHL, nb1, pw1fH, pw1fL, pb1,
                                                 pw2fH, pw2fL, pb2, p16);

    head_kernel<<<512, 256, 0, stream>>>(p16, bary1, off1, fw2T,fb2,fw3T,fb3,fw4,fb4, out);
}